// Round 10
// baseline (1047.402 us; speedup 1.0000x reference)
//
#include <hip/hip_runtime.h>
#include <math.h>

#define NSEQ 8192
#define BATCH 4
#define DIM 256
#define HEADS 8
#define DHEAD 32
#define NB 110
#define INNER 256
#define FFDIM 1024
#define MROWS (BATCH * NSEQ)   // 32768 rows
#define BH (BATCH * HEADS)     // 32

typedef __attribute__((ext_vector_type(8))) short bf16x8;
typedef __attribute__((ext_vector_type(4))) short bf16x4;
typedef __attribute__((ext_vector_type(4))) float f32x4;

typedef __attribute__((address_space(1))) const void* gas_cvp;
typedef __attribute__((address_space(3))) void* las_vp;

constexpr float c_dn = 0.42044820762685725f;     // 32^-0.25
constexpr float c_diagf = 0.08838834764831845f;  // 0.5*dn*dn
constexpr float c_ratio = 0.09534625892455922f;  // 110^-0.5

__device__ __forceinline__ unsigned short f2b(float f) {
    unsigned u = __float_as_uint(f);
    unsigned r = (u + 0x7FFFu + ((u >> 16) & 1u)) >> 16;
    return (unsigned short)r;
}
__device__ __forceinline__ float b2f(unsigned short u) {
    return __uint_as_float((unsigned)u << 16);
}

// ---------------- util ----------------
__global__ __launch_bounds__(256) void copy4_kernel(const float4* __restrict__ src,
                                                    float4* __restrict__ dst, int n4) {
    int i = blockIdx.x * 256 + threadIdx.x;
    if (i < n4) dst[i] = src[i];
}
__global__ __launch_bounds__(256) void zero_kernel(float* __restrict__ p, int n) {
    int i = blockIdx.x * 256 + threadIdx.x;
    if (i < n) p[i] = 0.0f;
}
__global__ __launch_bounds__(256) void bcat_kernel(const float* __restrict__ bq,
                                                   const float* __restrict__ bk,
                                                   const float* __restrict__ bv,
                                                   float* __restrict__ out) {
    int l = blockIdx.x, t = threadIdx.x;
    out[l * 768 + t] = bq[l * 256 + t];
    out[l * 768 + 256 + t] = bk[l * 256 + t];
    out[l * 768 + 512 + t] = bv[l * 256 + t];
}

// ---------------- LayerNorm: f32 in -> bf16 out ----------------
__global__ __launch_bounds__(256) void ln_kernel(const float* __restrict__ x,
                                                 const float* __restrict__ g,
                                                 const float* __restrict__ bta,
                                                 unsigned short* __restrict__ y) {
    int wave = threadIdx.x >> 6, lane = threadIdx.x & 63;
    int row = blockIdx.x * 4 + wave;
    const float* xr = x + (size_t)row * DIM;
    float4 v = *(const float4*)(xr + lane * 4);
    float s = v.x + v.y + v.z + v.w;
    float sq = v.x * v.x + v.y * v.y + v.z * v.z + v.w * v.w;
    #pragma unroll
    for (int off = 32; off; off >>= 1) {
        s += __shfl_xor(s, off);
        sq += __shfl_xor(sq, off);
    }
    float mean = s * (1.0f / DIM);
    float var = sq * (1.0f / DIM) - mean * mean;
    float rstd = rsqrtf(var + 1e-5f);
    float4 gg = *(const float4*)(g + lane * 4);
    float4 bb = *(const float4*)(bta + lane * 4);
    bf16x4 o;
    o[0] = (short)f2b((v.x - mean) * rstd * gg.x + bb.x);
    o[1] = (short)f2b((v.y - mean) * rstd * gg.y + bb.y);
    o[2] = (short)f2b((v.z - mean) * rstd * gg.z + bb.z);
    o[3] = (short)f2b((v.w - mean) * rstd * gg.w + bb.w);
    *(bf16x4*)(y + (size_t)row * DIM + lane * 4) = o;
}

// ---------------- weight transpose+convert: out[l][n][k] = bf16(in[l][k][n]) ----------------
__global__ __launch_bounds__(256) void wt_kernel(const float* __restrict__ in,
                                                 unsigned short* __restrict__ out,
                                                 int K, int Nn, int lstride) {
    __shared__ float t32[32][33];
    int l = blockIdx.z;
    const float* inp = in + (size_t)l * K * Nn;
    unsigned short* outp = out + (size_t)l * lstride;
    int k0 = blockIdx.x * 32, n0 = blockIdx.y * 32;
    int tx = threadIdx.x & 31, ty = threadIdx.x >> 5;
    #pragma unroll
    for (int i = 0; i < 4; ++i)
        t32[ty + i * 8][tx] = inp[(size_t)(k0 + ty + i * 8) * Nn + n0 + tx];
    __syncthreads();
    #pragma unroll
    for (int i = 0; i < 4; ++i) {
        int r = ty + i * 8;  // n within tile
        outp[(size_t)(n0 + r) * K + k0 + tx] = f2b(t32[tx][r]);
    }
}

// ---------------- bf16 MFMA GEMM with global_load_lds staging ----------------
// EPI 0: +bias -> bf16   EPI 1: +bias+res(f32) -> f32   EPI 2: gelu(+bias) -> bf16
// EPI 3: +bias -> bf16 segmented (col>>8 selects q/k/v plane of stride MROWS*DIM)
template <int EPI>
__global__ __launch_bounds__(256) void gemm_mfma(const unsigned short* __restrict__ A,
                                                 const unsigned short* __restrict__ Wt,
                                                 const float* __restrict__ bias,
                                                 const float* __restrict__ res,
                                                 void* __restrict__ Cv,
                                                 int Nn, int K) {
    __shared__ __align__(16) unsigned short As[128 * 32];
    __shared__ __align__(16) unsigned short Bs[128 * 32];
    int tid = threadIdx.x;
    int m0 = blockIdx.y * 128, n0 = blockIdx.x * 128;
    int wave = tid >> 6, lane = tid & 63;
    int wm = (wave >> 1) * 64, wn = (wave & 1) * 64;
    int lr = lane & 15, lg = lane >> 4;
    f32x4 acc[4][4];
    #pragma unroll
    for (int i = 0; i < 4; ++i)
        #pragma unroll
        for (int j = 0; j < 4; ++j) acc[i][j] = (f32x4){0.f, 0.f, 0.f, 0.f};

    int rowS[2], chS[2];
    #pragma unroll
    for (int j = 0; j < 2; ++j) {
        int f = wave * 128 + j * 64 + lane;
        rowS[j] = f >> 2;
        chS[j] = ((f & 3) ^ ((rowS[j] >> 1) & 3)) * 8;
    }
    int rdA[4], rdB[4];
    #pragma unroll
    for (int i = 0; i < 4; ++i) {
        int ra = wm + i * 16 + lr;
        rdA[i] = ra * 32 + (lg ^ ((ra >> 1) & 3)) * 8;
        int rb = wn + i * 16 + lr;
        rdB[i] = rb * 32 + (lg ^ ((rb >> 1) & 3)) * 8;
    }

    for (int kt = 0; kt < K; kt += 32) {
        #pragma unroll
        for (int j = 0; j < 2; ++j) {
            const unsigned short* srcA = A + (size_t)(m0 + rowS[j]) * K + kt + chS[j];
            __builtin_amdgcn_global_load_lds((gas_cvp)srcA,
                                             (las_vp)(As + wave * 1024 + j * 512), 16, 0, 0);
            const unsigned short* srcB = Wt + (size_t)(n0 + rowS[j]) * K + kt + chS[j];
            __builtin_amdgcn_global_load_lds((gas_cvp)srcB,
                                             (las_vp)(Bs + wave * 1024 + j * 512), 16, 0, 0);
        }
        __syncthreads();
        bf16x8 af[4], bfv[4];
        #pragma unroll
        for (int i = 0; i < 4; ++i) af[i] = *(bf16x8*)&As[rdA[i]];
        #pragma unroll
        for (int j = 0; j < 4; ++j) bfv[j] = *(bf16x8*)&Bs[rdB[j]];
        #pragma unroll
        for (int i = 0; i < 4; ++i)
            #pragma unroll
            for (int j = 0; j < 4; ++j)
                acc[i][j] = __builtin_amdgcn_mfma_f32_16x16x32_bf16(af[i], bfv[j], acc[i][j], 0, 0, 0);
        __syncthreads();
    }
    #pragma unroll
    for (int i = 0; i < 4; ++i) {
        #pragma unroll
        for (int j = 0; j < 4; ++j) {
            int col = n0 + wn + j * 16 + lr;
            float bv = bias[col];
            #pragma unroll
            for (int r = 0; r < 4; ++r) {
                int row = m0 + wm + i * 16 + lg * 4 + r;
                float c = acc[i][j][r] + bv;
                if (EPI == 1) {
                    c += res[(size_t)row * Nn + col];
                    ((float*)Cv)[(size_t)row * Nn + col] = c;
                } else if (EPI == 2) {
                    float u = c;
                    float t = 1.5957691216057308f * (u + 0.044715f * u * u * u);
                    float gv = u / (1.0f + __expf(-t));
                    ((unsigned short*)Cv)[(size_t)row * Nn + col] = f2b(gv);
                } else if (EPI == 3) {
                    size_t idx = (size_t)(col >> 8) * ((size_t)MROWS * DIM) + (size_t)row * 256 + (col & 255);
                    ((unsigned short*)Cv)[idx] = f2b(c);
                } else {
                    ((unsigned short*)Cv)[(size_t)row * Nn + col] = f2b(c);
                }
            }
        }
    }
}

// ---------------- fused FFN: h += W2 @ gelu(W1 @ y + b1) + b2 ----------------
// 32-row blocks (grid 1024). Per 128-col chunk of FFDIM: FFN1 MFMA -> gelu -> MidT (LDS),
// then 4x32 K-substeps of FFN2 accumulate into persistent acc2. mid never touches HBM.
__global__ __launch_bounds__(256) void ffn_kernel(const unsigned short* __restrict__ y,
                                                  const unsigned short* __restrict__ W1t,  // [1024][256]
                                                  const unsigned short* __restrict__ W2t,  // [256][1024]
                                                  const float* __restrict__ b1,
                                                  const float* __restrict__ b2,
                                                  float* __restrict__ h) {
    __shared__ __align__(16) unsigned short As[32 * 32];    // y k-tile
    __shared__ __align__(16) unsigned short Bs[128 * 32];   // W1t chunk k-tile
    __shared__ __align__(16) unsigned short Ws[256 * 32];   // W2t k-tile
    __shared__ unsigned short MidT[32][136];                // gelu(mid) chunk
    int tid = threadIdx.x;
    int m0 = blockIdx.x * 32;
    int wave = tid >> 6, lane = tid & 63;
    int wrow = wave >> 1, wcol = wave & 1;
    int lr = lane & 15, lg = lane >> 4;

    f32x4 acc2[8];
    #pragma unroll
    for (int j = 0; j < 8; ++j) acc2[j] = (f32x4){0.f, 0.f, 0.f, 0.f};

    // staging geometry
    // As: 32 rows -> 128 granules; wave stages 32 (lanes<32)
    int fA = wave * 32 + (lane & 31);
    int rowA = fA >> 2, chA = ((fA & 3) ^ ((rowA >> 1) & 3)) * 8;
    // Bs: 128 rows -> 512 granules; wave stages 128 (2/lane)
    int rowB[2], chB[2];
    #pragma unroll
    for (int j = 0; j < 2; ++j) {
        int f = wave * 128 + j * 64 + lane;
        rowB[j] = f >> 2;
        chB[j] = ((f & 3) ^ ((rowB[j] >> 1) & 3)) * 8;
    }
    // Ws: 256 rows -> 1024 granules; wave stages 256 (4/lane)
    int rowW[4], chW[4];
    #pragma unroll
    for (int j = 0; j < 4; ++j) {
        int f = wave * 256 + j * 64 + lane;
        rowW[j] = f >> 2;
        chW[j] = ((f & 3) ^ ((rowW[j] >> 1) & 3)) * 8;
    }
    // read offsets
    int raA = wrow * 16 + lr;                       // FFN1 A row (0..31)
    int rdAo = raA * 32 + (lg ^ ((raA >> 1) & 3)) * 8;
    int rdBo[4];
    #pragma unroll
    for (int j = 0; j < 4; ++j) {
        int rb = wcol * 64 + j * 16 + lr;           // FFN1 B row (0..127)
        rdBo[j] = rb * 32 + (lg ^ ((rb >> 1) & 3)) * 8;
    }
    int rdWo[8];
    #pragma unroll
    for (int j = 0; j < 8; ++j) {
        int nw = wcol * 128 + j * 16 + lr;          // FFN2 B row (0..255)
        rdWo[j] = nw * 32 + (lg ^ ((nw >> 1) & 3)) * 8;
    }

    for (int nc = 0; nc < 8; ++nc) {
        // ---- FFN1: mid chunk [32][128] ----
        f32x4 macc[4];
        #pragma unroll
        for (int j = 0; j < 4; ++j) macc[j] = (f32x4){0.f, 0.f, 0.f, 0.f};
        for (int kt = 0; kt < 8; ++kt) {
            if ((lane & 63) < 32) {
                const unsigned short* srcA = y + (size_t)(m0 + rowA) * 256 + kt * 32 + chA;
                __builtin_amdgcn_global_load_lds((gas_cvp)srcA,
                                                 (las_vp)(As + wave * 256), 16, 0, 0);
            }
            #pragma unroll
            for (int j = 0; j < 2; ++j) {
                const unsigned short* srcB = W1t + (size_t)(nc * 128 + rowB[j]) * 256 + kt * 32 + chB[j];
                __builtin_amdgcn_global_load_lds((gas_cvp)srcB,
                                                 (las_vp)(Bs + wave * 1024 + j * 512), 16, 0, 0);
            }
            __syncthreads();
            bf16x8 a1 = *(bf16x8*)&As[rdAo];
            #pragma unroll
            for (int j = 0; j < 4; ++j) {
                bf16x8 b1f = *(bf16x8*)&Bs[rdBo[j]];
                macc[j] = __builtin_amdgcn_mfma_f32_16x16x32_bf16(a1, b1f, macc[j], 0, 0, 0);
            }
            __syncthreads();
        }
        // bias + gelu -> MidT
        #pragma unroll
        for (int j = 0; j < 4; ++j) {
            int mc = wcol * 64 + j * 16 + lr;
            float bv = b1[nc * 128 + mc];
            #pragma unroll
            for (int r = 0; r < 4; ++r) {
                int mr = wrow * 16 + lg * 4 + r;
                float u = macc[j][r] + bv;
                float t = 1.5957691216057308f * (u + 0.044715f * u * u * u);
                float gv = u / (1.0f + __expf(-t));
                MidT[mr][mc] = f2b(gv);
            }
        }
        __syncthreads();
        // ---- FFN2 partial over this chunk's 128 K ----
        for (int ks = 0; ks < 4; ++ks) {
            #pragma unroll
            for (int j = 0; j < 4; ++j) {
                const unsigned short* srcW = W2t + (size_t)rowW[j] * 1024 + nc * 128 + ks * 32 + chW[j];
                __builtin_amdgcn_global_load_lds((gas_cvp)srcW,
                                                 (las_vp)(Ws + wave * 2048 + j * 512), 16, 0, 0);
            }
            __syncthreads();
            bf16x8 a2 = *(bf16x8*)&MidT[wrow * 16 + lr][ks * 32 + lg * 8];
            #pragma unroll
            for (int j = 0; j < 8; ++j) {
                bf16x8 b2f = *(bf16x8*)&Ws[rdWo[j]];
                acc2[j] = __builtin_amdgcn_mfma_f32_16x16x32_bf16(a2, b2f, acc2[j], 0, 0, 0);
            }
            __syncthreads();   // also protects MidT before next chunk rewrites it
        }
    }
    // epilogue: h += acc2 + b2
    #pragma unroll
    for (int j = 0; j < 8; ++j) {
        int col = wcol * 128 + j * 16 + lr;
        float bv = b2[col];
        #pragma unroll
        for (int r = 0; r < 4; ++r) {
            int row = m0 + wrow * 16 + lg * 4 + r;
            size_t idx = (size_t)row * 256 + col;
            h[idx] = h[idx] + acc2[j][r] + bv;
        }
    }
}

// ---------------- kmaxg ----------------
__global__ __launch_bounds__(256) void kmaxg_kernel(const unsigned short* __restrict__ k,
                                                    const float* __restrict__ proj,
                                                    float* __restrict__ partial) {
    __shared__ unsigned short As[128][40];
    __shared__ unsigned short Pj[112][40];
    __shared__ float wmax[4][8];
    int tid = threadIdx.x;
    int r0 = blockIdx.x * 128;
    for (int idx = tid; idx < 112 * 8; idx += 256) {
        int m = idx >> 3, f4 = idx & 7;
        if (m < NB) {
            float4 va = *(const float4*)(proj + m * 32 + f4 * 4);
            bf16x4 pk = {(short)f2b(va.x), (short)f2b(va.y), (short)f2b(va.z), (short)f2b(va.w)};
            *(bf16x4*)&Pj[m][f4 * 4] = pk;
        } else {
            *(bf16x4*)&Pj[m][f4 * 4] = (bf16x4){0, 0, 0, 0};
        }
    }
    int arow = tid >> 1, ahalf = tid & 1;
    const unsigned short* ap = k + (size_t)(r0 + arow) * 32 + ahalf * 16;
    *(bf16x8*)&As[arow][ahalf * 16] = *(const bf16x8*)ap;
    *(bf16x8*)&As[arow][ahalf * 16 + 8] = *(const bf16x8*)(ap + 8);
    __syncthreads();
    int wave = tid >> 6, lane = tid & 63, lr = lane & 15, lg = lane >> 4;
    float mymax[4] = {-1e30f, -1e30f, -1e30f, -1e30f};
    #pragma unroll
    for (int mt = 0; mt < 2; ++mt) {
        bf16x8 af = *(bf16x8*)&As[(2 * wave + mt) * 16 + lr][lg * 8];
        #pragma unroll
        for (int nt = 0; nt < 7; ++nt) {
            bf16x8 bfp = *(bf16x8*)&Pj[nt * 16 + lr][lg * 8];
            f32x4 d = (f32x4){0.f, 0.f, 0.f, 0.f};
            d = __builtin_amdgcn_mfma_f32_16x16x32_bf16(af, bfp, d, 0, 0, 0);
            if (!(nt == 6 && lr >= 14)) {
                #pragma unroll
                for (int r = 0; r < 4; ++r) mymax[r] = fmaxf(mymax[r], d[r]);
            }
        }
    }
    #pragma unroll
    for (int r = 0; r < 4; ++r) {
        float v = mymax[r];
        v = fmaxf(v, __shfl_xor(v, 1));
        v = fmaxf(v, __shfl_xor(v, 2));
        v = fmaxf(v, __shfl_xor(v, 4));
        v = fmaxf(v, __shfl_xor(v, 8));
        v = fmaxf(v, __shfl_xor(v, 32));
        mymax[r] = v;
    }
    if (lane == 0 || lane == 16) {
        int hb = (lane >> 4) & 1;
        #pragma unroll
        for (int r = 0; r < 4; ++r) wmax[wave][4 * hb + r] = mymax[r];
    }
    __syncthreads();
    if (tid < 8) {
        float m = fmaxf(fmaxf(wmax[0][tid], wmax[1][tid]), fmaxf(wmax[2][tid], wmax[3][tid]));
        partial[blockIdx.x * 8 + tid] = m * c_dn;
    }
}

// ---------------- kreduce ----------------
__global__ __launch_bounds__(256) void kreduce_kernel(const float* __restrict__ partial,
                                                      float* __restrict__ kmaxf) {
    __shared__ float wred[4];
    int bh = blockIdx.x, b = bh >> 3, h = bh & 7;
    int tid = threadIdx.x;
    float m = fmaxf(partial[(b * 512 + tid) * 8 + h], partial[(b * 512 + 256 + tid) * 8 + h]);
    #pragma unroll
    for (int off = 32; off; off >>= 1) m = fmaxf(m, __shfl_xor(m, off));
    if ((tid & 63) == 0) wred[tid >> 6] = m;
    __syncthreads();
    if (tid == 0)
        kmaxf[bh] = fmaxf(fmaxf(wred[0], wred[1]), fmaxf(wred[2], wred[3]));
}

// ---------------- ctxg ----------------
__global__ __launch_bounds__(256) void ctxg_kernel(const unsigned short* __restrict__ k,
                                                   const unsigned short* __restrict__ v,
                                                   const float* __restrict__ proj,
                                                   const float* __restrict__ kmaxf,
                                                   float* __restrict__ ctx) {
    __shared__ __align__(16) char pool[34816];
    unsigned short (*As)[40] = (unsigned short(*)[40])pool;
    unsigned short (*KpT)[136] = (unsigned short(*)[136])pool;
    __shared__ unsigned short Pj[112][40];
    __shared__ unsigned short VsT[48][136];
    __shared__ float dg[128];
    int tid = threadIdx.x;
    int bh = blockIdx.y, b = bh >> 3, h = bh & 7;
    int n_base = blockIdx.x * 512;
    float mx = kmaxf[bh];
    for (int idx = tid; idx < 112 * 8; idx += 256) {
        int m = idx >> 3, f4 = idx & 7;
        if (m < NB) {
            float4 va = *(const float4*)(proj + m * 32 + f4 * 4);
            bf16x4 pk = {(short)f2b(va.x), (short)f2b(va.y), (short)f2b(va.z), (short)f2b(va.w)};
            *(bf16x4*)&Pj[m][f4 * 4] = pk;
        } else {
            *(bf16x4*)&Pj[m][f4 * 4] = (bf16x4){0, 0, 0, 0};
        }
    }
    for (int idx = tid; idx < 16 * 136; idx += 256) KpT[112 + idx / 136][idx % 136] = 0;
    for (int idx = tid; idx < 16 * 128; idx += 256) {
        int rr = 32 + (idx >> 7), nn = idx & 127;
        VsT[rr][nn] = (rr == 32) ? (unsigned short)0x3F80 : (unsigned short)0;
    }
    int wave = tid >> 6, lane = tid & 63, lr = lane & 15, lg = lane >> 4;
    int arow = tid >> 1, ahalf = tid & 1;
    f32x4 ctxacc[2][3];
    #pragma unroll
    for (int mt = 0; mt < 2; ++mt)
        #pragma unroll
        for (int nt = 0; nt < 3; ++nt) ctxacc[mt][nt] = (f32x4){0.f, 0.f, 0.f, 0.f};

    for (int ni = 0; ni < 4; ++ni) {
        int n0 = n_base + ni * 128;
        {
            const unsigned short* kp_ = k + ((size_t)(b * NSEQ + n0 + arow) * 256 + h * 32 + ahalf * 16);
            bf16x8 k0 = *(const bf16x8*)kp_;
            bf16x8 k1 = *(const bf16x8*)(kp_ + 8);
            *(bf16x8*)&As[arow][ahalf * 16] = k0;
            *(bf16x8*)&As[arow][ahalf * 16 + 8] = k1;
            float ssq = 0.f;
            #pragma unroll
            for (int e = 0; e < 8; ++e) {
                float a = b2f((unsigned short)k0[e]), bb = b2f((unsigned short)k1[e]);
                ssq += a * a + bb * bb;
            }
            ssq += __shfl_xor(ssq, 1);
            if (ahalf == 0) dg[arow] = ssq * c_diagf;
        }
        #pragma unroll
        for (int it = 0; it < 4; ++it) {
            int idx = it * 256 + tid;
            int nn = idx >> 3, f4 = idx & 7;
            bf16x4 vv = *(const bf16x4*)(v + ((size_t)(b * NSEQ + n0 + nn) * 256 + h * 32 + f4 * 4));
            VsT[f4 * 4 + 0][nn] = (unsigned short)vv[0];
            VsT[f4 * 4 + 1][nn] = (unsigned short)vv[1];
            VsT[f4 * 4 + 2][nn] = (unsigned short)vv[2];
            VsT[f4 * 4 + 3][nn] = (unsigned short)vv[3];
        }
        __syncthreads();
        f32x4 xds[2][7];
        #pragma unroll
        for (int mt = 0; mt < 2; ++mt) {
            bf16x8 af = *(bf16x8*)&As[(2 * wave + mt) * 16 + lr][lg * 8];
            #pragma unroll
            for (int nt = 0; nt < 7; ++nt) {
                bf16x8 bfp = *(bf16x8*)&Pj[nt * 16 + lr][lg * 8];
                f32x4 d = (f32x4){0.f, 0.f, 0.f, 0.f};
                xds[mt][nt] = __builtin_amdgcn_mfma_f32_16x16x32_bf16(af, bfp, d, 0, 0, 0);
            }
        }
        __syncthreads();
        #pragma unroll
        for (int mt = 0; mt < 2; ++mt)
            #pragma unroll
            for (int nt = 0; nt < 7; ++nt) {
                int m = nt * 16 + lr;
                #pragma unroll
                for (int r = 0; r < 4; ++r) {
                    int nn = (2 * wave + mt) * 16 + lg * 4 + r;
                    float kpv = (m < NB) ? c_ratio * (__expf(xds[mt][nt][r] * c_dn - dg[nn] - mx) + 1e-4f) : 0.f;
                    KpT[m][nn] = f2b(kpv);
                }
            }
        __syncthreads();
        #pragma unroll
        for (int ks = 0; ks < 4; ++ks)
            #pragma unroll
            for (int mt = 0; mt < 2; ++mt) {
                bf16x8 af2 = *(bf16x8*)&KpT[(2 * wave + mt) * 16 + lr][ks * 32 + lg * 8];
                #pragma unroll
                for (int nt = 0; nt < 3; ++nt) {
                    bf16x8 bf2v = *(bf16x8*)&VsT[nt * 16 + lr][ks * 32 + lg * 8];
                    ctxacc[mt][nt] = __builtin_amdgcn_mfma_f32_16x16x32_bf16(af2, bf2v, ctxacc[mt][nt], 0, 0, 0);
                }
            }
        __syncthreads();
    }
    #pragma unroll
    for (int mt = 0; mt < 2; ++mt)
        #pragma unroll
        for (int nt = 0; nt < 3; ++nt)
            #pragma unroll
            for (int r = 0; r < 4; ++r) {
                int m = (2 * wave + mt) * 16 + lg * 4 + r;
                atomicAdd(&ctx[((size_t)bh * 128 + m) * 48 + nt * 16 + lr], ctxacc[mt][nt][r]);
            }
}

// ---------------- og ----------------
__global__ __launch_bounds__(256) void og_kernel(const unsigned short* __restrict__ q,
                                                 const float* __restrict__ proj,
                                                 const float* __restrict__ ctx,
                                                 unsigned short* __restrict__ o) {
    __shared__ __align__(16) char pool[34816];
    unsigned short (*As)[40] = (unsigned short(*)[40])pool;
    unsigned short (*Qp)[136] = (unsigned short(*)[136])pool;
    __shared__ unsigned short Pj[112][40];
    __shared__ unsigned short CsT[48][136];
    __shared__ float dg[128];
    int tid = threadIdx.x;
    int bh = blockIdx.x >> 6, b = bh >> 3, h = bh & 7;
    int n0 = (blockIdx.x & 63) * 128;
    for (int idx = tid; idx < 112 * 8; idx += 256) {
        int m = idx >> 3, f4 = idx & 7;
        if (m < NB) {
            float4 va = *(const float4*)(proj + m * 32 + f4 * 4);
            bf16x4 pk = {(short)f2b(va.x), (short)f2b(va.y), (short)f2b(va.z), (short)f2b(va.w)};
            *(bf16x4*)&Pj[m][f4 * 4] = pk;
        } else {
            *(bf16x4*)&Pj[m][f4 * 4] = (bf16x4){0, 0, 0, 0};
        }
    }
    for (int idx = tid; idx < 128 * 12; idx += 256) {
        int m = idx / 12, c4 = idx - m * 12;
        float4 cv = *(const float4*)(ctx + ((size_t)bh * 128 + m) * 48 + c4 * 4);
        CsT[c4 * 4 + 0][m] = f2b(cv.x);
        CsT[c4 * 4 + 1][m] = f2b(cv.y);
        CsT[c4 * 4 + 2][m] = f2b(cv.z);
        CsT[c4 * 4 + 3][m] = f2b(cv.w);
    }
    int arow = tid >> 1, ahalf = tid & 1;
    {
        const unsigned short* qp_ = q + ((size_t)(b * NSEQ + n0 + arow) * 256 + h * 32 + ahalf * 16);
        bf16x8 q0 = *(const bf16x8*)qp_;
        bf16x8 q1 = *(const bf16x8*)(qp_ + 8);
        *(bf16x8*)&As[arow][ahalf * 16] = q0;
        *(bf16x8*)&As[arow][ahalf * 16 + 8] = q1;
        float ssq = 0.f;
        #pragma unroll
        for (int e = 0; e < 8; ++e) {
            float a = b2f((unsigned short)q0[e]), bb = b2f((unsigned short)q1[e]);
            ssq += a * a + bb * bb;
        }
        ssq += __shfl_xor(ssq, 1);
        if (ahalf == 0) dg[arow] = ssq * c_diagf;
    }
    __syncthreads();
    int wave = tid >> 6, lane = tid & 63, lr = lane & 15, lg = lane >> 4;
    f32x4 xds[2][7];
    #pragma unroll
    for (int mt = 0; mt < 2; ++mt) {
        bf16x8 af = *(bf16x8*)&As[(2 * wave + mt) * 16 + lr][lg * 8];
        #pragma unroll
        for (int nt = 0; nt < 7; ++nt) {
            bf16x8 bfp = *(bf16x8*)&Pj[nt * 16 + lr][lg * 8];
            f32x4 d = (f32x4){0.f, 0.f, 0.f, 0.f};
            xds[mt][nt] = __builtin_amdgcn_mfma_f32_16x16x32_bf16(af, bfp, d, 0, 0, 0);
        }
    }
    float rmax[2][4];
    #pragma unroll
    for (int mt = 0; mt < 2; ++mt)
        #pragma unroll
        for (int r = 0; r < 4; ++r) {
            float mv = -1e30f;
            #pragma unroll
            for (int nt = 0; nt < 7; ++nt)
                if (!(nt == 6 && lr >= 14)) mv = fmaxf(mv, xds[mt][nt][r]);
            mv = fmaxf(mv, __shfl_xor(mv, 1));
            mv = fmaxf(mv, __shfl_xor(mv, 2));
            mv = fmaxf(mv, __shfl_xor(mv, 4));
            mv = fmaxf(mv, __shfl_xor(mv, 8));
            rmax[mt][r] = mv;
        }
    __syncthreads();
    #pragma unroll
    for (int mt = 0; mt < 2; ++mt)
        #pragma unroll
        for (int r = 0; r < 4; ++r) {
            int row = (2 * wave + mt) * 16 + lg * 4 + r;
            #pragma unroll
            for (int nt = 0; nt < 7; ++nt) {
                int m = nt * 16 + lr;
                float qpv = (m < NB)
                    ? c_ratio * (__expf((xds[mt][nt][r] - rmax[mt][r]) * c_dn - dg[row]) + 1e-4f)
                    : 0.f;
                Qp[row][m] = f2b(qpv);
            }
            Qp[row][112 + lr] = 0;
        }
    __syncthreads();
    f32x4 oacc[2][3];
    #pragma unroll
    for (int mt = 0; mt < 2; ++mt)
        #pragma unroll
        for (int nt = 0; nt < 3; ++nt) oacc[mt][nt] = (f32x4){0.f, 0.f, 0.f, 0.f};
    #pragma unroll
    for (int ks = 0; ks < 4; ++ks)
        #pragma unroll
        for (int mt = 0; mt < 2; ++mt) {
            bf16x8 af2 = *(bf16x8*)&Qp[(2 * wave + mt) * 16 + lr][ks * 32 + lg * 8];
            #pragma unroll
            for (int nt = 0; nt < 3; ++nt) {
                bf16x8 bf2v = *(bf16x8*)&CsT[nt * 16 + lr][ks * 32 + lg * 8];
                oacc[mt][nt] = __builtin_amdgcn_mfma_f32_16x16x32_bf16(af2, bf2v, oacc[mt][nt], 0, 0, 0);
            }
        }
    #pragma unroll
    for (int mt = 0; mt < 2; ++mt)
        #pragma unroll
        for (int r = 0; r < 4; ++r) {
            int row = (2 * wave + mt) * 16 + lg * 4 + r;
            int n = n0 + row;
            float den = __shfl(oacc[mt][2][r], lane & 48);
            float inv = 1.0f / den;
            size_t base = (size_t)(b * NSEQ + n) * 256 + h * 32;
            o[base + lr] = f2b(oacc[mt][0][r] * inv);
            o[base + 16 + lr] = f2b(oacc[mt][1][r] * inv);
        }
}

extern "C" void kernel_launch(void* const* d_in, const int* in_sizes, int n_in,
                              void* d_out, int out_size, void* d_ws, size_t ws_size,
                              hipStream_t stream) {
    const float* x = (const float*)d_in[0];
    const float* proj = (const float*)d_in[1];
    const float* ln1_g = (const float*)d_in[2];
    const float* ln1_b = (const float*)d_in[3];
    const float* Wq = (const float*)d_in[4];
    const float* bq = (const float*)d_in[5];
    const float* Wk = (const float*)d_in[6];
    const float* bk = (const float*)d_in[7];
    const float* Wv = (const float*)d_in[8];
    const float* bv = (const float*)d_in[9];
    const float* Wo = (const float*)d_in[10];
    const float* bo = (const float*)d_in[11];
    const float* ln2_g = (const float*)d_in[12];
    const float* ln2_b = (const float*)d_in[13];
    const float* Wf1 = (const float*)d_in[14];
    const float* bf1 = (const float*)d_in[15];
    const float* Wf2 = (const float*)d_in[16];
    const float* bf2 = (const float*)d_in[17];

    float* h = (float*)d_out;
    const size_t ACT = (size_t)MROWS * DIM;
    unsigned short* y = (unsigned short*)d_ws;
    unsigned short* q = y + ACT;
    unsigned short* k = q + ACT;
    unsigned short* v = k + ACT;
    unsigned short* mid = v + ACT;                   // unused now (kept for layout stability)
    float* ctx = (float*)(mid + 4 * ACT);
    float* kmaxf = ctx + (size_t)BH * 128 * 48;
    float* partial = kmaxf + 32;                     // 2048*8 floats
    float* bqkv = partial + 2048 * 8;                // 4*768 floats
    unsigned short* wt = (unsigned short*)(bqkv + 4 * 768);
    unsigned short* o = y;

    const int WT_L = 786432;
    const int CTXN = BH * 128 * 48;

    copy4_kernel<<<(int)(ACT / 4) / 256, 256, 0, stream>>>((const float4*)x, (float4*)h, (int)(ACT / 4));

    wt_kernel<<<dim3(8, 8, 4), 256, 0, stream>>>(Wq, wt + 0, 256, 256, WT_L);
    wt_kernel<<<dim3(8, 8, 4), 256, 0, stream>>>(Wk, wt + 65536, 256, 256, WT_L);
    wt_kernel<<<dim3(8, 8, 4), 256, 0, stream>>>(Wv, wt + 131072, 256, 256, WT_L);
    wt_kernel<<<dim3(8, 8, 4), 256, 0, stream>>>(Wo, wt + 196608, 256, 256, WT_L);
    wt_kernel<<<dim3(8, 32, 4), 256, 0, stream>>>(Wf1, wt + 262144, 256, 1024, WT_L);
    wt_kernel<<<dim3(32, 8, 4), 256, 0, stream>>>(Wf2, wt + 524288, 1024, 256, WT_L);
    bcat_kernel<<<4, 256, 0, stream>>>(bq, bk, bv, bqkv);

    for (int i = 0; i < 4; ++i) {
        const float* proj_i = proj + (size_t)i * NB * DHEAD;
        const unsigned short* wl = wt + (size_t)i * WT_L;
        // --- attention ---
        ln_kernel<<<MROWS / 4, 256, 0, stream>>>(h, ln1_g + i * DIM, ln1_b + i * DIM, y);
        // fused QKV: Wt rows 0..767 = [Wq;Wk;Wv], segmented output into q|k|v planes
        gemm_mfma<3><<<dim3(6, 256), 256, 0, stream>>>(y, wl + 0, bqkv + i * 768, nullptr, q, 768, DIM);

        zero_kernel<<<(CTXN + 255) / 256, 256, 0, stream>>>(ctx, CTXN);
        kmaxg_kernel<<<2048, 256, 0, stream>>>(k, proj_i, partial);
        kreduce_kernel<<<BH, 256, 0, stream>>>(partial, kmaxf);
        ctxg_kernel<<<dim3(16, BH), 256, 0, stream>>>(k, v, proj_i, kmaxf, ctx);
        og_kernel<<<BH * 64, 256, 0, stream>>>(q, proj_i, ctx, o);

        gemm_mfma<1><<<dim3(2, 256), 256, 0, stream>>>(o, wl + 196608, bo + i * DIM, h, h, DIM, INNER);

        // --- fused FFN ---
        ln_kernel<<<MROWS / 4, 256, 0, stream>>>(h, ln2_g + i * DIM, ln2_b + i * DIM, y);
        ffn_kernel<<<MROWS / 32, 256, 0, stream>>>(y, wl + 262144, wl + 524288,
                                                   bf1 + i * FFDIM, bf2 + i * DIM, h);
    }
}

// Round 11
// 901.567 us; speedup vs baseline: 1.1618x; 1.1618x over previous
//
#include <hip/hip_runtime.h>
#include <math.h>

#define NSEQ 8192
#define BATCH 4
#define DIM 256
#define HEADS 8
#define DHEAD 32
#define NB 110
#define INNER 256
#define FFDIM 1024
#define MROWS (BATCH * NSEQ)   // 32768 rows
#define BH (BATCH * HEADS)     // 32

typedef __attribute__((ext_vector_type(8))) short bf16x8;
typedef __attribute__((ext_vector_type(4))) short bf16x4;
typedef __attribute__((ext_vector_type(4))) float f32x4;

typedef __attribute__((address_space(1))) const void* gas_cvp;
typedef __attribute__((address_space(3))) void* las_vp;

constexpr float c_dn = 0.42044820762685725f;     // 32^-0.25
constexpr float c_diagf = 0.08838834764831845f;  // 0.5*dn*dn
constexpr float c_ratio = 0.09534625892455922f;  // 110^-0.5

__device__ __forceinline__ unsigned short f2b(float f) {
    unsigned u = __float_as_uint(f);
    unsigned r = (u + 0x7FFFu + ((u >> 16) & 1u)) >> 16;
    return (unsigned short)r;
}
__device__ __forceinline__ float b2f(unsigned short u) {
    return __uint_as_float((unsigned)u << 16);
}

// ---------------- util ----------------
__global__ __launch_bounds__(256) void copy4_kernel(const float4* __restrict__ src,
                                                    float4* __restrict__ dst, int n4) {
    int i = blockIdx.x * 256 + threadIdx.x;
    if (i < n4) dst[i] = src[i];
}
__global__ __launch_bounds__(256) void zero_kernel(float* __restrict__ p, int n) {
    int i = blockIdx.x * 256 + threadIdx.x;
    if (i < n) p[i] = 0.0f;
}
__global__ __launch_bounds__(256) void bcat_kernel(const float* __restrict__ bq,
                                                   const float* __restrict__ bk,
                                                   const float* __restrict__ bv,
                                                   float* __restrict__ out) {
    int l = blockIdx.x, t = threadIdx.x;
    out[l * 768 + t] = bq[l * 256 + t];
    out[l * 768 + 256 + t] = bk[l * 256 + t];
    out[l * 768 + 512 + t] = bv[l * 256 + t];
}

// ---------------- LayerNorm: f32 in -> bf16 out ----------------
__global__ __launch_bounds__(256) void ln_kernel(const float* __restrict__ x,
                                                 const float* __restrict__ g,
                                                 const float* __restrict__ bta,
                                                 unsigned short* __restrict__ y) {
    int wave = threadIdx.x >> 6, lane = threadIdx.x & 63;
    int row = blockIdx.x * 4 + wave;
    const float* xr = x + (size_t)row * DIM;
    float4 v = *(const float4*)(xr + lane * 4);
    float s = v.x + v.y + v.z + v.w;
    float sq = v.x * v.x + v.y * v.y + v.z * v.z + v.w * v.w;
    #pragma unroll
    for (int off = 32; off; off >>= 1) {
        s += __shfl_xor(s, off);
        sq += __shfl_xor(sq, off);
    }
    float mean = s * (1.0f / DIM);
    float var = sq * (1.0f / DIM) - mean * mean;
    float rstd = rsqrtf(var + 1e-5f);
    float4 gg = *(const float4*)(g + lane * 4);
    float4 bb = *(const float4*)(bta + lane * 4);
    bf16x4 o;
    o[0] = (short)f2b((v.x - mean) * rstd * gg.x + bb.x);
    o[1] = (short)f2b((v.y - mean) * rstd * gg.y + bb.y);
    o[2] = (short)f2b((v.z - mean) * rstd * gg.z + bb.z);
    o[3] = (short)f2b((v.w - mean) * rstd * gg.w + bb.w);
    *(bf16x4*)(y + (size_t)row * DIM + lane * 4) = o;
}

// ---------------- weight transpose+convert: out[l][n][k] = bf16(in[l][k][n]) ----------------
__global__ __launch_bounds__(256) void wt_kernel(const float* __restrict__ in,
                                                 unsigned short* __restrict__ out,
                                                 int K, int Nn, int lstride) {
    __shared__ float t32[32][33];
    int l = blockIdx.z;
    const float* inp = in + (size_t)l * K * Nn;
    unsigned short* outp = out + (size_t)l * lstride;
    int k0 = blockIdx.x * 32, n0 = blockIdx.y * 32;
    int tx = threadIdx.x & 31, ty = threadIdx.x >> 5;
    #pragma unroll
    for (int i = 0; i < 4; ++i)
        t32[ty + i * 8][tx] = inp[(size_t)(k0 + ty + i * 8) * Nn + n0 + tx];
    __syncthreads();
    #pragma unroll
    for (int i = 0; i < 4; ++i) {
        int r = ty + i * 8;  // n within tile
        outp[(size_t)(n0 + r) * K + k0 + tx] = f2b(t32[tx][r]);
    }
}

// ---------------- bf16 MFMA GEMM, double-buffered global_load_lds + counted vmcnt ----------------
// EPI 0: +bias -> bf16   EPI 1: +bias+res(f32) -> f32   EPI 2: gelu(+bias) -> bf16
// EPI 3: +bias -> bf16 segmented (col>>8 selects q/k/v plane of stride MROWS*DIM)
// 2-phase pipeline (T3/T4 minimal): stage tile kt+1 FIRST, then wait vmcnt(4) (= tile kt's
// 4 loads, issued one full iteration ago) + raw barrier; MFMA on tile kt; raw end-barrier
// guards buf[kt] against kt+1's restage. Full vmcnt(0) drain only on the last tile.
template <int EPI>
__global__ __launch_bounds__(256) void gemm_mfma(const unsigned short* __restrict__ A,
                                                 const unsigned short* __restrict__ Wt,
                                                 const float* __restrict__ bias,
                                                 const float* __restrict__ res,
                                                 void* __restrict__ Cv,
                                                 int Nn, int K) {
    __shared__ __align__(16) unsigned short As[2][128 * 32];
    __shared__ __align__(16) unsigned short Bs[2][128 * 32];
    int tid = threadIdx.x;
    int m0 = blockIdx.y * 128, n0 = blockIdx.x * 128;
    int wave = tid >> 6, lane = tid & 63;
    int wm = (wave >> 1) * 64, wn = (wave & 1) * 64;
    int lr = lane & 15, lg = lane >> 4;
    f32x4 acc[4][4];
    #pragma unroll
    for (int i = 0; i < 4; ++i)
        #pragma unroll
        for (int j = 0; j < 4; ++j) acc[i][j] = (f32x4){0.f, 0.f, 0.f, 0.f};

    int rowS[2], chS[2];
    #pragma unroll
    for (int j = 0; j < 2; ++j) {
        int f = wave * 128 + j * 64 + lane;
        rowS[j] = f >> 2;
        chS[j] = ((f & 3) ^ ((rowS[j] >> 1) & 3)) * 8;
    }
    int rdA[4], rdB[4];
    #pragma unroll
    for (int i = 0; i < 4; ++i) {
        int ra = wm + i * 16 + lr;
        rdA[i] = ra * 32 + (lg ^ ((ra >> 1) & 3)) * 8;
        int rb = wn + i * 16 + lr;
        rdB[i] = rb * 32 + (lg ^ ((rb >> 1) & 3)) * 8;
    }

    const int NT = K >> 5;
    // prologue: stage tile 0 into buffer 0
    #pragma unroll
    for (int j = 0; j < 2; ++j) {
        const unsigned short* srcA = A + (size_t)(m0 + rowS[j]) * K + chS[j];
        __builtin_amdgcn_global_load_lds((gas_cvp)srcA,
                                         (las_vp)(&As[0][wave * 1024 + j * 512]), 16, 0, 0);
        const unsigned short* srcB = Wt + (size_t)(n0 + rowS[j]) * K + chS[j];
        __builtin_amdgcn_global_load_lds((gas_cvp)srcB,
                                         (las_vp)(&Bs[0][wave * 1024 + j * 512]), 16, 0, 0);
    }
    for (int kt = 0; kt < NT; ++kt) {
        int cur = kt & 1;
        if (kt + 1 < NT) {
            int nxt = cur ^ 1;
            int koff = (kt + 1) * 32;
            #pragma unroll
            for (int j = 0; j < 2; ++j) {
                const unsigned short* srcA = A + (size_t)(m0 + rowS[j]) * K + koff + chS[j];
                __builtin_amdgcn_global_load_lds((gas_cvp)srcA,
                                                 (las_vp)(&As[nxt][wave * 1024 + j * 512]), 16, 0, 0);
                const unsigned short* srcB = Wt + (size_t)(n0 + rowS[j]) * K + koff + chS[j];
                __builtin_amdgcn_global_load_lds((gas_cvp)srcB,
                                                 (las_vp)(&Bs[nxt][wave * 1024 + j * 512]), 16, 0, 0);
            }
            asm volatile("s_waitcnt vmcnt(4)" ::: "memory");
        } else {
            asm volatile("s_waitcnt vmcnt(0)" ::: "memory");
        }
        __builtin_amdgcn_s_barrier();
        __builtin_amdgcn_sched_barrier(0);
        bf16x8 af[4], bfv[4];
        #pragma unroll
        for (int i = 0; i < 4; ++i) af[i] = *(bf16x8*)&As[cur][rdA[i]];
        #pragma unroll
        for (int j = 0; j < 4; ++j) bfv[j] = *(bf16x8*)&Bs[cur][rdB[j]];
        #pragma unroll
        for (int i = 0; i < 4; ++i)
            #pragma unroll
            for (int j = 0; j < 4; ++j)
                acc[i][j] = __builtin_amdgcn_mfma_f32_16x16x32_bf16(af[i], bfv[j], acc[i][j], 0, 0, 0);
        __builtin_amdgcn_sched_barrier(0);
        __builtin_amdgcn_s_barrier();
    }
    #pragma unroll
    for (int i = 0; i < 4; ++i) {
        #pragma unroll
        for (int j = 0; j < 4; ++j) {
            int col = n0 + wn + j * 16 + lr;
            float bv = bias[col];
            #pragma unroll
            for (int r = 0; r < 4; ++r) {
                int row = m0 + wm + i * 16 + lg * 4 + r;
                float c = acc[i][j][r] + bv;
                if (EPI == 1) {
                    c += res[(size_t)row * Nn + col];
                    ((float*)Cv)[(size_t)row * Nn + col] = c;
                } else if (EPI == 2) {
                    float u = c;
                    float t = 1.5957691216057308f * (u + 0.044715f * u * u * u);
                    float gv = u / (1.0f + __expf(-t));
                    ((unsigned short*)Cv)[(size_t)row * Nn + col] = f2b(gv);
                } else if (EPI == 3) {
                    size_t idx = (size_t)(col >> 8) * ((size_t)MROWS * DIM) + (size_t)row * 256 + (col & 255);
                    ((unsigned short*)Cv)[idx] = f2b(c);
                } else {
                    ((unsigned short*)Cv)[(size_t)row * Nn + col] = f2b(c);
                }
            }
        }
    }
}

// ---------------- kmaxg ----------------
__global__ __launch_bounds__(256) void kmaxg_kernel(const unsigned short* __restrict__ k,
                                                    const float* __restrict__ proj,
                                                    float* __restrict__ partial) {
    __shared__ unsigned short As[128][40];
    __shared__ unsigned short Pj[112][40];
    __shared__ float wmax[4][8];
    int tid = threadIdx.x;
    int r0 = blockIdx.x * 128;
    for (int idx = tid; idx < 112 * 8; idx += 256) {
        int m = idx >> 3, f4 = idx & 7;
        if (m < NB) {
            float4 va = *(const float4*)(proj + m * 32 + f4 * 4);
            bf16x4 pk = {(short)f2b(va.x), (short)f2b(va.y), (short)f2b(va.z), (short)f2b(va.w)};
            *(bf16x4*)&Pj[m][f4 * 4] = pk;
        } else {
            *(bf16x4*)&Pj[m][f4 * 4] = (bf16x4){0, 0, 0, 0};
        }
    }
    int arow = tid >> 1, ahalf = tid & 1;
    const unsigned short* ap = k + (size_t)(r0 + arow) * 32 + ahalf * 16;
    *(bf16x8*)&As[arow][ahalf * 16] = *(const bf16x8*)ap;
    *(bf16x8*)&As[arow][ahalf * 16 + 8] = *(const bf16x8*)(ap + 8);
    __syncthreads();
    int wave = tid >> 6, lane = tid & 63, lr = lane & 15, lg = lane >> 4;
    float mymax[4] = {-1e30f, -1e30f, -1e30f, -1e30f};
    #pragma unroll
    for (int mt = 0; mt < 2; ++mt) {
        bf16x8 af = *(bf16x8*)&As[(2 * wave + mt) * 16 + lr][lg * 8];
        #pragma unroll
        for (int nt = 0; nt < 7; ++nt) {
            bf16x8 bfp = *(bf16x8*)&Pj[nt * 16 + lr][lg * 8];
            f32x4 d = (f32x4){0.f, 0.f, 0.f, 0.f};
            d = __builtin_amdgcn_mfma_f32_16x16x32_bf16(af, bfp, d, 0, 0, 0);
            if (!(nt == 6 && lr >= 14)) {
                #pragma unroll
                for (int r = 0; r < 4; ++r) mymax[r] = fmaxf(mymax[r], d[r]);
            }
        }
    }
    #pragma unroll
    for (int r = 0; r < 4; ++r) {
        float v = mymax[r];
        v = fmaxf(v, __shfl_xor(v, 1));
        v = fmaxf(v, __shfl_xor(v, 2));
        v = fmaxf(v, __shfl_xor(v, 4));
        v = fmaxf(v, __shfl_xor(v, 8));
        v = fmaxf(v, __shfl_xor(v, 32));
        mymax[r] = v;
    }
    if (lane == 0 || lane == 16) {
        int hb = (lane >> 4) & 1;
        #pragma unroll
        for (int r = 0; r < 4; ++r) wmax[wave][4 * hb + r] = mymax[r];
    }
    __syncthreads();
    if (tid < 8) {
        float m = fmaxf(fmaxf(wmax[0][tid], wmax[1][tid]), fmaxf(wmax[2][tid], wmax[3][tid]));
        partial[blockIdx.x * 8 + tid] = m * c_dn;
    }
}

// ---------------- kreduce ----------------
__global__ __launch_bounds__(256) void kreduce_kernel(const float* __restrict__ partial,
                                                      float* __restrict__ kmaxf) {
    __shared__ float wred[4];
    int bh = blockIdx.x, b = bh >> 3, h = bh & 7;
    int tid = threadIdx.x;
    float m = fmaxf(partial[(b * 512 + tid) * 8 + h], partial[(b * 512 + 256 + tid) * 8 + h]);
    #pragma unroll
    for (int off = 32; off; off >>= 1) m = fmaxf(m, __shfl_xor(m, off));
    if ((tid & 63) == 0) wred[tid >> 6] = m;
    __syncthreads();
    if (tid == 0)
        kmaxf[bh] = fmaxf(fmaxf(wred[0], wred[1]), fmaxf(wred[2], wred[3]));
}

// ---------------- ctxg ----------------
__global__ __launch_bounds__(256) void ctxg_kernel(const unsigned short* __restrict__ k,
                                                   const unsigned short* __restrict__ v,
                                                   const float* __restrict__ proj,
                                                   const float* __restrict__ kmaxf,
                                                   float* __restrict__ ctx) {
    __shared__ __align__(16) char pool[34816];
    unsigned short (*As)[40] = (unsigned short(*)[40])pool;
    unsigned short (*KpT)[136] = (unsigned short(*)[136])pool;
    __shared__ unsigned short Pj[112][40];
    __shared__ unsigned short VsT[48][136];
    __shared__ float dg[128];
    int tid = threadIdx.x;
    int bh = blockIdx.y, b = bh >> 3, h = bh & 7;
    int n_base = blockIdx.x * 512;
    float mx = kmaxf[bh];
    for (int idx = tid; idx < 112 * 8; idx += 256) {
        int m = idx >> 3, f4 = idx & 7;
        if (m < NB) {
            float4 va = *(const float4*)(proj + m * 32 + f4 * 4);
            bf16x4 pk = {(short)f2b(va.x), (short)f2b(va.y), (short)f2b(va.z), (short)f2b(va.w)};
            *(bf16x4*)&Pj[m][f4 * 4] = pk;
        } else {
            *(bf16x4*)&Pj[m][f4 * 4] = (bf16x4){0, 0, 0, 0};
        }
    }
    for (int idx = tid; idx < 16 * 136; idx += 256) KpT[112 + idx / 136][idx % 136] = 0;
    for (int idx = tid; idx < 16 * 128; idx += 256) {
        int rr = 32 + (idx >> 7), nn = idx & 127;
        VsT[rr][nn] = (rr == 32) ? (unsigned short)0x3F80 : (unsigned short)0;
    }
    int wave = tid >> 6, lane = tid & 63, lr = lane & 15, lg = lane >> 4;
    int arow = tid >> 1, ahalf = tid & 1;
    f32x4 ctxacc[2][3];
    #pragma unroll
    for (int mt = 0; mt < 2; ++mt)
        #pragma unroll
        for (int nt = 0; nt < 3; ++nt) ctxacc[mt][nt] = (f32x4){0.f, 0.f, 0.f, 0.f};

    for (int ni = 0; ni < 4; ++ni) {
        int n0 = n_base + ni * 128;
        {
            const unsigned short* kp_ = k + ((size_t)(b * NSEQ + n0 + arow) * 256 + h * 32 + ahalf * 16);
            bf16x8 k0 = *(const bf16x8*)kp_;
            bf16x8 k1 = *(const bf16x8*)(kp_ + 8);
            *(bf16x8*)&As[arow][ahalf * 16] = k0;
            *(bf16x8*)&As[arow][ahalf * 16 + 8] = k1;
            float ssq = 0.f;
            #pragma unroll
            for (int e = 0; e < 8; ++e) {
                float a = b2f((unsigned short)k0[e]), bb = b2f((unsigned short)k1[e]);
                ssq += a * a + bb * bb;
            }
            ssq += __shfl_xor(ssq, 1);
            if (ahalf == 0) dg[arow] = ssq * c_diagf;
        }
        #pragma unroll
        for (int it = 0; it < 4; ++it) {
            int idx = it * 256 + tid;
            int nn = idx >> 3, f4 = idx & 7;
            bf16x4 vv = *(const bf16x4*)(v + ((size_t)(b * NSEQ + n0 + nn) * 256 + h * 32 + f4 * 4));
            VsT[f4 * 4 + 0][nn] = (unsigned short)vv[0];
            VsT[f4 * 4 + 1][nn] = (unsigned short)vv[1];
            VsT[f4 * 4 + 2][nn] = (unsigned short)vv[2];
            VsT[f4 * 4 + 3][nn] = (unsigned short)vv[3];
        }
        __syncthreads();
        f32x4 xds[2][7];
        #pragma unroll
        for (int mt = 0; mt < 2; ++mt) {
            bf16x8 af = *(bf16x8*)&As[(2 * wave + mt) * 16 + lr][lg * 8];
            #pragma unroll
            for (int nt = 0; nt < 7; ++nt) {
                bf16x8 bfp = *(bf16x8*)&Pj[nt * 16 + lr][lg * 8];
                f32x4 d = (f32x4){0.f, 0.f, 0.f, 0.f};
                xds[mt][nt] = __builtin_amdgcn_mfma_f32_16x16x32_bf16(af, bfp, d, 0, 0, 0);
            }
        }
        __syncthreads();
        #pragma unroll
        for (int mt = 0; mt < 2; ++mt)
            #pragma unroll
            for (int nt = 0; nt < 7; ++nt) {
                int m = nt * 16 + lr;
                #pragma unroll
                for (int r = 0; r < 4; ++r) {
                    int nn = (2 * wave + mt) * 16 + lg * 4 + r;
                    float kpv = (m < NB) ? c_ratio * (__expf(xds[mt][nt][r] * c_dn - dg[nn] - mx) + 1e-4f) : 0.f;
                    KpT[m][nn] = f2b(kpv);
                }
            }
        __syncthreads();
        #pragma unroll
        for (int ks = 0; ks < 4; ++ks)
            #pragma unroll
            for (int mt = 0; mt < 2; ++mt) {
                bf16x8 af2 = *(bf16x8*)&KpT[(2 * wave + mt) * 16 + lr][ks * 32 + lg * 8];
                #pragma unroll
                for (int nt = 0; nt < 3; ++nt) {
                    bf16x8 bf2v = *(bf16x8*)&VsT[nt * 16 + lr][ks * 32 + lg * 8];
                    ctxacc[mt][nt] = __builtin_amdgcn_mfma_f32_16x16x32_bf16(af2, bf2v, ctxacc[mt][nt], 0, 0, 0);
                }
            }
        __syncthreads();
    }
    #pragma unroll
    for (int mt = 0; mt < 2; ++mt)
        #pragma unroll
        for (int nt = 0; nt < 3; ++nt)
            #pragma unroll
            for (int r = 0; r < 4; ++r) {
                int m = (2 * wave + mt) * 16 + lg * 4 + r;
                atomicAdd(&ctx[((size_t)bh * 128 + m) * 48 + nt * 16 + lr], ctxacc[mt][nt][r]);
            }
}

// ---------------- og ----------------
__global__ __launch_bounds__(256) void og_kernel(const unsigned short* __restrict__ q,
                                                 const float* __restrict__ proj,
                                                 const float* __restrict__ ctx,
                                                 unsigned short* __restrict__ o) {
    __shared__ __align__(16) char pool[34816];
    unsigned short (*As)[40] = (unsigned short(*)[40])pool;
    unsigned short (*Qp)[136] = (unsigned short(*)[136])pool;
    __shared__ unsigned short Pj[112][40];
    __shared__ unsigned short CsT[48][136];
    __shared__ float dg[128];
    int tid = threadIdx.x;
    int bh = blockIdx.x >> 6, b = bh >> 3, h = bh & 7;
    int n0 = (blockIdx.x & 63) * 128;
    for (int idx = tid; idx < 112 * 8; idx += 256) {
        int m = idx >> 3, f4 = idx & 7;
        if (m < NB) {
            float4 va = *(const float4*)(proj + m * 32 + f4 * 4);
            bf16x4 pk = {(short)f2b(va.x), (short)f2b(va.y), (short)f2b(va.z), (short)f2b(va.w)};
            *(bf16x4*)&Pj[m][f4 * 4] = pk;
        } else {
            *(bf16x4*)&Pj[m][f4 * 4] = (bf16x4){0, 0, 0, 0};
        }
    }
    for (int idx = tid; idx < 128 * 12; idx += 256) {
        int m = idx / 12, c4 = idx - m * 12;
        float4 cv = *(const float4*)(ctx + ((size_t)bh * 128 + m) * 48 + c4 * 4);
        CsT[c4 * 4 + 0][m] = f2b(cv.x);
        CsT[c4 * 4 + 1][m] = f2b(cv.y);
        CsT[c4 * 4 + 2][m] = f2b(cv.z);
        CsT[c4 * 4 + 3][m] = f2b(cv.w);
    }
    int arow = tid >> 1, ahalf = tid & 1;
    {
        const unsigned short* qp_ = q + ((size_t)(b * NSEQ + n0 + arow) * 256 + h * 32 + ahalf * 16);
        bf16x8 q0 = *(const bf16x8*)qp_;
        bf16x8 q1 = *(const bf16x8*)(qp_ + 8);
        *(bf16x8*)&As[arow][ahalf * 16] = q0;
        *(bf16x8*)&As[arow][ahalf * 16 + 8] = q1;
        float ssq = 0.f;
        #pragma unroll
        for (int e = 0; e < 8; ++e) {
            float a = b2f((unsigned short)q0[e]), bb = b2f((unsigned short)q1[e]);
            ssq += a * a + bb * bb;
        }
        ssq += __shfl_xor(ssq, 1);
        if (ahalf == 0) dg[arow] = ssq * c_diagf;
    }
    __syncthreads();
    int wave = tid >> 6, lane = tid & 63, lr = lane & 15, lg = lane >> 4;
    f32x4 xds[2][7];
    #pragma unroll
    for (int mt = 0; mt < 2; ++mt) {
        bf16x8 af = *(bf16x8*)&As[(2 * wave + mt) * 16 + lr][lg * 8];
        #pragma unroll
        for (int nt = 0; nt < 7; ++nt) {
            bf16x8 bfp = *(bf16x8*)&Pj[nt * 16 + lr][lg * 8];
            f32x4 d = (f32x4){0.f, 0.f, 0.f, 0.f};
            xds[mt][nt] = __builtin_amdgcn_mfma_f32_16x16x32_bf16(af, bfp, d, 0, 0, 0);
        }
    }
    float rmax[2][4];
    #pragma unroll
    for (int mt = 0; mt < 2; ++mt)
        #pragma unroll
        for (int r = 0; r < 4; ++r) {
            float mv = -1e30f;
            #pragma unroll
            for (int nt = 0; nt < 7; ++nt)
                if (!(nt == 6 && lr >= 14)) mv = fmaxf(mv, xds[mt][nt][r]);
            mv = fmaxf(mv, __shfl_xor(mv, 1));
            mv = fmaxf(mv, __shfl_xor(mv, 2));
            mv = fmaxf(mv, __shfl_xor(mv, 4));
            mv = fmaxf(mv, __shfl_xor(mv, 8));
            rmax[mt][r] = mv;
        }
    __syncthreads();
    #pragma unroll
    for (int mt = 0; mt < 2; ++mt)
        #pragma unroll
        for (int r = 0; r < 4; ++r) {
            int row = (2 * wave + mt) * 16 + lg * 4 + r;
            #pragma unroll
            for (int nt = 0; nt < 7; ++nt) {
                int m = nt * 16 + lr;
                float qpv = (m < NB)
                    ? c_ratio * (__expf((xds[mt][nt][r] - rmax[mt][r]) * c_dn - dg[row]) + 1e-4f)
                    : 0.f;
                Qp[row][m] = f2b(qpv);
            }
            Qp[row][112 + lr] = 0;
        }
    __syncthreads();
    f32x4 oacc[2][3];
    #pragma unroll
    for (int mt = 0; mt < 2; ++mt)
        #pragma unroll
        for (int nt = 0; nt < 3; ++nt) oacc[mt][nt] = (f32x4){0.f, 0.f, 0.f, 0.f};
    #pragma unroll
    for (int ks = 0; ks < 4; ++ks)
        #pragma unroll
        for (int mt = 0; mt < 2; ++mt) {
            bf16x8 af2 = *(bf16x8*)&Qp[(2 * wave + mt) * 16 + lr][ks * 32 + lg * 8];
            #pragma unroll
            for (int nt = 0; nt < 3; ++nt) {
                bf16x8 bf2v = *(bf16x8*)&CsT[nt * 16 + lr][ks * 32 + lg * 8];
                oacc[mt][nt] = __builtin_amdgcn_mfma_f32_16x16x32_bf16(af2, bf2v, oacc[mt][nt], 0, 0, 0);
            }
        }
    #pragma unroll
    for (int mt = 0; mt < 2; ++mt)
        #pragma unroll
        for (int r = 0; r < 4; ++r) {
            int row = (2 * wave + mt) * 16 + lg * 4 + r;
            int n = n0 + row;
            float den = __shfl(oacc[mt][2][r], lane & 48);
            float inv = 1.0f / den;
            size_t base = (size_t)(b * NSEQ + n) * 256 + h * 32;
            o[base + lr] = f2b(oacc[mt][0][r] * inv);
            o[base + 16 + lr] = f2b(oacc[mt][1][r] * inv);
        }
}

extern "C" void kernel_launch(void* const* d_in, const int* in_sizes, int n_in,
                              void* d_out, int out_size, void* d_ws, size_t ws_size,
                              hipStream_t stream) {
    const float* x = (const float*)d_in[0];
    const float* proj = (const float*)d_in[1];
    const float* ln1_g = (const float*)d_in[2];
    const float* ln1_b = (const float*)d_in[3];
    const float* Wq = (const float*)d_in[4];
    const float* bq = (const float*)d_in[5];
    const float* Wk = (const float*)d_in[6];
    const float* bk = (const float*)d_in[7];
    const float* Wv = (const float*)d_in[8];
    const float* bv = (const float*)d_in[9];
    const float* Wo = (const float*)d_in[10];
    const float* bo = (const float*)d_in[11];
    const float* ln2_g = (const float*)d_in[12];
    const float* ln2_b = (const float*)d_in[13];
    const float* Wf1 = (const float*)d_in[14];
    const float* bf1 = (const float*)d_in[15];
    const float* Wf2 = (const float*)d_in[16];
    const float* bf2 = (const float*)d_in[17];

    float* h = (float*)d_out;
    const size_t ACT = (size_t)MROWS * DIM;
    unsigned short* y = (unsigned short*)d_ws;
    unsigned short* q = y + ACT;
    unsigned short* k = q + ACT;
    unsigned short* v = k + ACT;
    unsigned short* mid = v + ACT;                   // [32768][1024] bf16
    float* ctx = (float*)(mid + 4 * ACT);
    float* kmaxf = ctx + (size_t)BH * 128 * 48;
    float* partial = kmaxf + 32;                     // 2048*8 floats
    float* bqkv = partial + 2048 * 8;                // 4*768 floats
    unsigned short* wt = (unsigned short*)(bqkv + 4 * 768);
    unsigned short* o = y;

    const int WT_L = 786432;
    const int CTXN = BH * 128 * 48;

    copy4_kernel<<<(int)(ACT / 4) / 256, 256, 0, stream>>>((const float4*)x, (float4*)h, (int)(ACT / 4));

    wt_kernel<<<dim3(8, 8, 4), 256, 0, stream>>>(Wq, wt + 0, 256, 256, WT_L);
    wt_kernel<<<dim3(8, 8, 4), 256, 0, stream>>>(Wk, wt + 65536, 256, 256, WT_L);
    wt_kernel<<<dim3(8, 8, 4), 256, 0, stream>>>(Wv, wt + 131072, 256, 256, WT_L);
    wt_kernel<<<dim3(8, 8, 4), 256, 0, stream>>>(Wo, wt + 196608, 256, 256, WT_L);
    wt_kernel<<<dim3(8, 32, 4), 256, 0, stream>>>(Wf1, wt + 262144, 256, 1024, WT_L);
    wt_kernel<<<dim3(32, 8, 4), 256, 0, stream>>>(Wf2, wt + 524288, 1024, 256, WT_L);
    bcat_kernel<<<4, 256, 0, stream>>>(bq, bk, bv, bqkv);

    for (int i = 0; i < 4; ++i) {
        const float* proj_i = proj + (size_t)i * NB * DHEAD;
        const unsigned short* wl = wt + (size_t)i * WT_L;
        // --- attention ---
        ln_kernel<<<MROWS / 4, 256, 0, stream>>>(h, ln1_g + i * DIM, ln1_b + i * DIM, y);
        gemm_mfma<3><<<dim3(6, 256), 256, 0, stream>>>(y, wl + 0, bqkv + i * 768, nullptr, q, 768, DIM);

        zero_kernel<<<(CTXN + 255) / 256, 256, 0, stream>>>(ctx, CTXN);
        kmaxg_kernel<<<2048, 256, 0, stream>>>(k, proj_i, partial);
        kreduce_kernel<<<BH, 256, 0, stream>>>(partial, kmaxf);
        ctxg_kernel<<<dim3(16, BH), 256, 0, stream>>>(k, v, proj_i, kmaxf, ctx);
        og_kernel<<<BH * 64, 256, 0, stream>>>(q, proj_i, ctx, o);

        gemm_mfma<1><<<dim3(2, 256), 256, 0, stream>>>(o, wl + 196608, bo + i * DIM, h, h, DIM, INNER);

        // --- FFN (separate GEMMs; fusion regressed in R10) ---
        ln_kernel<<<MROWS / 4, 256, 0, stream>>>(h, ln2_g + i * DIM, ln2_b + i * DIM, y);
        gemm_mfma<2><<<dim3(8, 256), 256, 0, stream>>>(y, wl + 262144, bf1 + i * FFDIM, nullptr, mid, FFDIM, DIM);
        gemm_mfma<1><<<dim3(2, 256), 256, 0, stream>>>(mid, wl + 524288, bf2 + i * DIM, h, h, DIM, FFDIM);
    }
}

// Round 12
// 892.314 us; speedup vs baseline: 1.1738x; 1.0104x over previous
//
#include <hip/hip_runtime.h>
#include <math.h>

#define NSEQ 8192
#define BATCH 4
#define DIM 256
#define HEADS 8
#define DHEAD 32
#define NB 110
#define INNER 256
#define FFDIM 1024
#define MROWS (BATCH * NSEQ)   // 32768 rows
#define BH (BATCH * HEADS)     // 32

typedef __attribute__((ext_vector_type(8))) short bf16x8;
typedef __attribute__((ext_vector_type(4))) short bf16x4;
typedef __attribute__((ext_vector_type(4))) float f32x4;

typedef __attribute__((address_space(1))) const void* gas_cvp;
typedef __attribute__((address_space(3))) void* las_vp;

constexpr float c_dn = 0.42044820762685725f;     // 32^-0.25
constexpr float c_diagf = 0.08838834764831845f;  // 0.5*dn*dn
constexpr float c_ratio = 0.09534625892455922f;  // 110^-0.5

__device__ __forceinline__ unsigned short f2b(float f) {
    unsigned u = __float_as_uint(f);
    unsigned r = (u + 0x7FFFu + ((u >> 16) & 1u)) >> 16;
    return (unsigned short)r;
}
__device__ __forceinline__ float b2f(unsigned short u) {
    return __uint_as_float((unsigned)u << 16);
}

// ---------------- util ----------------
__global__ __launch_bounds__(256) void copy4_kernel(const float4* __restrict__ src,
                                                    float4* __restrict__ dst, int n4) {
    int i = blockIdx.x * 256 + threadIdx.x;
    if (i < n4) dst[i] = src[i];
}
__global__ __launch_bounds__(256) void zero_kernel(float* __restrict__ p, int n) {
    int i = blockIdx.x * 256 + threadIdx.x;
    if (i < n) p[i] = 0.0f;
}
__global__ __launch_bounds__(256) void bcat_kernel(const float* __restrict__ bq,
                                                   const float* __restrict__ bk,
                                                   const float* __restrict__ bv,
                                                   float* __restrict__ out) {
    int l = blockIdx.x, t = threadIdx.x;
    out[l * 768 + t] = bq[l * 256 + t];
    out[l * 768 + 256 + t] = bk[l * 256 + t];
    out[l * 768 + 512 + t] = bv[l * 256 + t];
}

// ---------------- LayerNorm: f32 in -> bf16 out ----------------
__global__ __launch_bounds__(256) void ln_kernel(const float* __restrict__ x,
                                                 const float* __restrict__ g,
                                                 const float* __restrict__ bta,
                                                 unsigned short* __restrict__ y) {
    int wave = threadIdx.x >> 6, lane = threadIdx.x & 63;
    int row = blockIdx.x * 4 + wave;
    const float* xr = x + (size_t)row * DIM;
    float4 v = *(const float4*)(xr + lane * 4);
    float s = v.x + v.y + v.z + v.w;
    float sq = v.x * v.x + v.y * v.y + v.z * v.z + v.w * v.w;
    #pragma unroll
    for (int off = 32; off; off >>= 1) {
        s += __shfl_xor(s, off);
        sq += __shfl_xor(sq, off);
    }
    float mean = s * (1.0f / DIM);
    float var = sq * (1.0f / DIM) - mean * mean;
    float rstd = rsqrtf(var + 1e-5f);
    float4 gg = *(const float4*)(g + lane * 4);
    float4 bb = *(const float4*)(bta + lane * 4);
    bf16x4 o;
    o[0] = (short)f2b((v.x - mean) * rstd * gg.x + bb.x);
    o[1] = (short)f2b((v.y - mean) * rstd * gg.y + bb.y);
    o[2] = (short)f2b((v.z - mean) * rstd * gg.z + bb.z);
    o[3] = (short)f2b((v.w - mean) * rstd * gg.w + bb.w);
    *(bf16x4*)(y + (size_t)row * DIM + lane * 4) = o;
}

// ---------------- weight transpose+convert: out[l][n][k] = bf16(in[l][k][n]) ----------------
__global__ __launch_bounds__(256) void wt_kernel(const float* __restrict__ in,
                                                 unsigned short* __restrict__ out,
                                                 int K, int Nn, int lstride) {
    __shared__ float t32[32][33];
    int l = blockIdx.z;
    const float* inp = in + (size_t)l * K * Nn;
    unsigned short* outp = out + (size_t)l * lstride;
    int k0 = blockIdx.x * 32, n0 = blockIdx.y * 32;
    int tx = threadIdx.x & 31, ty = threadIdx.x >> 5;
    #pragma unroll
    for (int i = 0; i < 4; ++i)
        t32[ty + i * 8][tx] = inp[(size_t)(k0 + ty + i * 8) * Nn + n0 + tx];
    __syncthreads();
    #pragma unroll
    for (int i = 0; i < 4; ++i) {
        int r = ty + i * 8;  // n within tile
        outp[(size_t)(n0 + r) * K + k0 + tx] = f2b(t32[tx][r]);
    }
}

// ---------------- bf16 MFMA GEMM, double-buffered global_load_lds + counted vmcnt ----------------
// EPI 0: +bias -> bf16   EPI 1: +bias+res(f32) -> f32   EPI 2: gelu(+bias) -> bf16
// EPI 3: +bias -> bf16 segmented (col>>8 selects q/k/v plane of stride MROWS*DIM)
// bf16 EPIs (0/2/3) use an LDS-transposed epilogue: acc -> swizzled LDS C-tile -> coalesced
// bf16x8 stores (1KB/wave-instr). EPI 1 (f32+res) keeps the scalar path.
template <int EPI>
__global__ __launch_bounds__(256) void gemm_mfma(const unsigned short* __restrict__ A,
                                                 const unsigned short* __restrict__ Wt,
                                                 const float* __restrict__ bias,
                                                 const float* __restrict__ res,
                                                 void* __restrict__ Cv,
                                                 int Nn, int K) {
    __shared__ __align__(16) unsigned short pool[16384];   // As[2][4096] | Bs[2][4096]; reused as C[128][128]
    unsigned short* AsP = pool;          // + buf*4096
    unsigned short* BsP = pool + 8192;   // + buf*4096
    int tid = threadIdx.x;
    int m0 = blockIdx.y * 128, n0 = blockIdx.x * 128;
    int wave = tid >> 6, lane = tid & 63;
    int wm = (wave >> 1) * 64, wn = (wave & 1) * 64;
    int lr = lane & 15, lg = lane >> 4;
    f32x4 acc[4][4];
    #pragma unroll
    for (int i = 0; i < 4; ++i)
        #pragma unroll
        for (int j = 0; j < 4; ++j) acc[i][j] = (f32x4){0.f, 0.f, 0.f, 0.f};

    int rowS[2], chS[2];
    #pragma unroll
    for (int j = 0; j < 2; ++j) {
        int f = wave * 128 + j * 64 + lane;
        rowS[j] = f >> 2;
        chS[j] = ((f & 3) ^ ((rowS[j] >> 1) & 3)) * 8;
    }
    int rdA[4], rdB[4];
    #pragma unroll
    for (int i = 0; i < 4; ++i) {
        int ra = wm + i * 16 + lr;
        rdA[i] = ra * 32 + (lg ^ ((ra >> 1) & 3)) * 8;
        int rb = wn + i * 16 + lr;
        rdB[i] = rb * 32 + (lg ^ ((rb >> 1) & 3)) * 8;
    }

    const int NT = K >> 5;
    #pragma unroll
    for (int j = 0; j < 2; ++j) {
        const unsigned short* srcA = A + (size_t)(m0 + rowS[j]) * K + chS[j];
        __builtin_amdgcn_global_load_lds((gas_cvp)srcA,
                                         (las_vp)(AsP + wave * 1024 + j * 512), 16, 0, 0);
        const unsigned short* srcB = Wt + (size_t)(n0 + rowS[j]) * K + chS[j];
        __builtin_amdgcn_global_load_lds((gas_cvp)srcB,
                                         (las_vp)(BsP + wave * 1024 + j * 512), 16, 0, 0);
    }
    for (int kt = 0; kt < NT; ++kt) {
        int cur = kt & 1;
        if (kt + 1 < NT) {
            int nxt = cur ^ 1;
            int koff = (kt + 1) * 32;
            #pragma unroll
            for (int j = 0; j < 2; ++j) {
                const unsigned short* srcA = A + (size_t)(m0 + rowS[j]) * K + koff + chS[j];
                __builtin_amdgcn_global_load_lds((gas_cvp)srcA,
                                                 (las_vp)(AsP + nxt * 4096 + wave * 1024 + j * 512), 16, 0, 0);
                const unsigned short* srcB = Wt + (size_t)(n0 + rowS[j]) * K + koff + chS[j];
                __builtin_amdgcn_global_load_lds((gas_cvp)srcB,
                                                 (las_vp)(BsP + nxt * 4096 + wave * 1024 + j * 512), 16, 0, 0);
            }
            asm volatile("s_waitcnt vmcnt(4)" ::: "memory");
        } else {
            asm volatile("s_waitcnt vmcnt(0)" ::: "memory");
        }
        __builtin_amdgcn_s_barrier();
        __builtin_amdgcn_sched_barrier(0);
        bf16x8 af[4], bfv[4];
        #pragma unroll
        for (int i = 0; i < 4; ++i) af[i] = *(bf16x8*)&AsP[cur * 4096 + rdA[i]];
        #pragma unroll
        for (int j = 0; j < 4; ++j) bfv[j] = *(bf16x8*)&BsP[cur * 4096 + rdB[j]];
        #pragma unroll
        for (int i = 0; i < 4; ++i)
            #pragma unroll
            for (int j = 0; j < 4; ++j)
                acc[i][j] = __builtin_amdgcn_mfma_f32_16x16x32_bf16(af[i], bfv[j], acc[i][j], 0, 0, 0);
        __builtin_amdgcn_sched_barrier(0);
        __builtin_amdgcn_s_barrier();
    }

    if (EPI == 1) {
        // scalar f32 epilogue (+bias+res)
        #pragma unroll
        for (int i = 0; i < 4; ++i) {
            #pragma unroll
            for (int j = 0; j < 4; ++j) {
                int col = n0 + wn + j * 16 + lr;
                float bv = bias[col];
                #pragma unroll
                for (int r = 0; r < 4; ++r) {
                    int row = m0 + wm + i * 16 + lg * 4 + r;
                    float c = acc[i][j][r] + bv + res[(size_t)row * Nn + col];
                    ((float*)Cv)[(size_t)row * Nn + col] = c;
                }
            }
        }
    } else {
        // LDS-transposed bf16 epilogue: pool becomes C[128][128] bf16, granule-swizzled.
        // short addr = trow*128 + ((chunk ^ (trow&7))<<3) + (tcol&7), chunk = tcol>>3.
        #pragma unroll
        for (int i = 0; i < 4; ++i) {
            #pragma unroll
            for (int j = 0; j < 4; ++j) {
                int tcol = wn + j * 16 + lr;
                float bv = bias[n0 + tcol];
                #pragma unroll
                for (int r = 0; r < 4; ++r) {
                    int trow = wm + i * 16 + lg * 4 + r;
                    float c = acc[i][j][r] + bv;
                    if (EPI == 2) {
                        float u = c;
                        float t = 1.5957691216057308f * (u + 0.044715f * u * u * u);
                        c = u / (1.0f + __expf(-t));
                    }
                    pool[trow * 128 + (((tcol >> 3) ^ (trow & 7)) << 3) + (tcol & 7)] = f2b(c);
                }
            }
        }
        __syncthreads();
        #pragma unroll
        for (int cch = 0; cch < 8; ++cch) {
            int g = cch * 256 + tid;          // granule id: 2048 = 128 rows x 16 chunks
            int row = g >> 4, cc = g & 15;
            bf16x8 val = *(bf16x8*)&pool[row * 128 + ((cc ^ (row & 7)) << 3)];
            int grow = m0 + row;
            int gcol = n0 + cc * 8;
            if (EPI == 3) {
                size_t idx = (size_t)(gcol >> 8) * ((size_t)MROWS * DIM) + (size_t)grow * 256 + (gcol & 255);
                *(bf16x8*)((unsigned short*)Cv + idx) = val;
            } else {
                *(bf16x8*)((unsigned short*)Cv + (size_t)grow * Nn + gcol) = val;
            }
        }
    }
}

// ---------------- kmaxg ----------------
__global__ __launch_bounds__(256) void kmaxg_kernel(const unsigned short* __restrict__ k,
                                                    const float* __restrict__ proj,
                                                    float* __restrict__ partial) {
    __shared__ unsigned short As[128][40];
    __shared__ unsigned short Pj[112][40];
    __shared__ float wmax[4][8];
    int tid = threadIdx.x;
    int r0 = blockIdx.x * 128;
    for (int idx = tid; idx < 112 * 8; idx += 256) {
        int m = idx >> 3, f4 = idx & 7;
        if (m < NB) {
            float4 va = *(const float4*)(proj + m * 32 + f4 * 4);
            bf16x4 pk = {(short)f2b(va.x), (short)f2b(va.y), (short)f2b(va.z), (short)f2b(va.w)};
            *(bf16x4*)&Pj[m][f4 * 4] = pk;
        } else {
            *(bf16x4*)&Pj[m][f4 * 4] = (bf16x4){0, 0, 0, 0};
        }
    }
    int arow = tid >> 1, ahalf = tid & 1;
    const unsigned short* ap = k + (size_t)(r0 + arow) * 32 + ahalf * 16;
    *(bf16x8*)&As[arow][ahalf * 16] = *(const bf16x8*)ap;
    *(bf16x8*)&As[arow][ahalf * 16 + 8] = *(const bf16x8*)(ap + 8);
    __syncthreads();
    int wave = tid >> 6, lane = tid & 63, lr = lane & 15, lg = lane >> 4;
    float mymax[4] = {-1e30f, -1e30f, -1e30f, -1e30f};
    #pragma unroll
    for (int mt = 0; mt < 2; ++mt) {
        bf16x8 af = *(bf16x8*)&As[(2 * wave + mt) * 16 + lr][lg * 8];
        #pragma unroll
        for (int nt = 0; nt < 7; ++nt) {
            bf16x8 bfp = *(bf16x8*)&Pj[nt * 16 + lr][lg * 8];
            f32x4 d = (f32x4){0.f, 0.f, 0.f, 0.f};
            d = __builtin_amdgcn_mfma_f32_16x16x32_bf16(af, bfp, d, 0, 0, 0);
            if (!(nt == 6 && lr >= 14)) {
                #pragma unroll
                for (int r = 0; r < 4; ++r) mymax[r] = fmaxf(mymax[r], d[r]);
            }
        }
    }
    #pragma unroll
    for (int r = 0; r < 4; ++r) {
        float v = mymax[r];
        v = fmaxf(v, __shfl_xor(v, 1));
        v = fmaxf(v, __shfl_xor(v, 2));
        v = fmaxf(v, __shfl_xor(v, 4));
        v = fmaxf(v, __shfl_xor(v, 8));
        v = fmaxf(v, __shfl_xor(v, 32));
        mymax[r] = v;
    }
    if (lane == 0 || lane == 16) {
        int hb = (lane >> 4) & 1;
        #pragma unroll
        for (int r = 0; r < 4; ++r) wmax[wave][4 * hb + r] = mymax[r];
    }
    __syncthreads();
    if (tid < 8) {
        float m = fmaxf(fmaxf(wmax[0][tid], wmax[1][tid]), fmaxf(wmax[2][tid], wmax[3][tid]));
        partial[blockIdx.x * 8 + tid] = m * c_dn;
    }
}

// ---------------- kreduce ----------------
__global__ __launch_bounds__(256) void kreduce_kernel(const float* __restrict__ partial,
                                                      float* __restrict__ kmaxf) {
    __shared__ float wred[4];
    int bh = blockIdx.x, b = bh >> 3, h = bh & 7;
    int tid = threadIdx.x;
    float m = fmaxf(partial[(b * 512 + tid) * 8 + h], partial[(b * 512 + 256 + tid) * 8 + h]);
    #pragma unroll
    for (int off = 32; off; off >>= 1) m = fmaxf(m, __shfl_xor(m, off));
    if ((tid & 63) == 0) wred[tid >> 6] = m;
    __syncthreads();
    if (tid == 0)
        kmaxf[bh] = fmaxf(fmaxf(wred[0], wred[1]), fmaxf(wred[2], wred[3]));
}

// ---------------- ctxg ----------------
__global__ __launch_bounds__(256) void ctxg_kernel(const unsigned short* __restrict__ k,
                                                   const unsigned short* __restrict__ v,
                                                   const float* __restrict__ proj,
                                                   const float* __restrict__ kmaxf,
                                                   float* __restrict__ ctx) {
    __shared__ __align__(16) char pool[34816];
    unsigned short (*As)[40] = (unsigned short(*)[40])pool;
    unsigned short (*KpT)[136] = (unsigned short(*)[136])pool;
    __shared__ unsigned short Pj[112][40];
    __shared__ unsigned short VsT[48][136];
    __shared__ float dg[128];
    int tid = threadIdx.x;
    int bh = blockIdx.y, b = bh >> 3, h = bh & 7;
    int n_base = blockIdx.x * 512;
    float mx = kmaxf[bh];
    for (int idx = tid; idx < 112 * 8; idx += 256) {
        int m = idx >> 3, f4 = idx & 7;
        if (m < NB) {
            float4 va = *(const float4*)(proj + m * 32 + f4 * 4);
            bf16x4 pk = {(short)f2b(va.x), (short)f2b(va.y), (short)f2b(va.z), (short)f2b(va.w)};
            *(bf16x4*)&Pj[m][f4 * 4] = pk;
        } else {
            *(bf16x4*)&Pj[m][f4 * 4] = (bf16x4){0, 0, 0, 0};
        }
    }
    for (int idx = tid; idx < 16 * 136; idx += 256) KpT[112 + idx / 136][idx % 136] = 0;
    for (int idx = tid; idx < 16 * 128; idx += 256) {
        int rr = 32 + (idx >> 7), nn = idx & 127;
        VsT[rr][nn] = (rr == 32) ? (unsigned short)0x3F80 : (unsigned short)0;
    }
    int wave = tid >> 6, lane = tid & 63, lr = lane & 15, lg = lane >> 4;
    int arow = tid >> 1, ahalf = tid & 1;
    f32x4 ctxacc[2][3];
    #pragma unroll
    for (int mt = 0; mt < 2; ++mt)
        #pragma unroll
        for (int nt = 0; nt < 3; ++nt) ctxacc[mt][nt] = (f32x4){0.f, 0.f, 0.f, 0.f};

    for (int ni = 0; ni < 4; ++ni) {
        int n0 = n_base + ni * 128;
        {
            const unsigned short* kp_ = k + ((size_t)(b * NSEQ + n0 + arow) * 256 + h * 32 + ahalf * 16);
            bf16x8 k0 = *(const bf16x8*)kp_;
            bf16x8 k1 = *(const bf16x8*)(kp_ + 8);
            *(bf16x8*)&As[arow][ahalf * 16] = k0;
            *(bf16x8*)&As[arow][ahalf * 16 + 8] = k1;
            float ssq = 0.f;
            #pragma unroll
            for (int e = 0; e < 8; ++e) {
                float a = b2f((unsigned short)k0[e]), bb = b2f((unsigned short)k1[e]);
                ssq += a * a + bb * bb;
            }
            ssq += __shfl_xor(ssq, 1);
            if (ahalf == 0) dg[arow] = ssq * c_diagf;
        }
        #pragma unroll
        for (int it = 0; it < 4; ++it) {
            int idx = it * 256 + tid;
            int nn = idx >> 3, f4 = idx & 7;
            bf16x4 vv = *(const bf16x4*)(v + ((size_t)(b * NSEQ + n0 + nn) * 256 + h * 32 + f4 * 4));
            VsT[f4 * 4 + 0][nn] = (unsigned short)vv[0];
            VsT[f4 * 4 + 1][nn] = (unsigned short)vv[1];
            VsT[f4 * 4 + 2][nn] = (unsigned short)vv[2];
            VsT[f4 * 4 + 3][nn] = (unsigned short)vv[3];
        }
        __syncthreads();
        f32x4 xds[2][7];
        #pragma unroll
        for (int mt = 0; mt < 2; ++mt) {
            bf16x8 af = *(bf16x8*)&As[(2 * wave + mt) * 16 + lr][lg * 8];
            #pragma unroll
            for (int nt = 0; nt < 7; ++nt) {
                bf16x8 bfp = *(bf16x8*)&Pj[nt * 16 + lr][lg * 8];
                f32x4 d = (f32x4){0.f, 0.f, 0.f, 0.f};
                xds[mt][nt] = __builtin_amdgcn_mfma_f32_16x16x32_bf16(af, bfp, d, 0, 0, 0);
            }
        }
        __syncthreads();
        #pragma unroll
        for (int mt = 0; mt < 2; ++mt)
            #pragma unroll
            for (int nt = 0; nt < 7; ++nt) {
                int m = nt * 16 + lr;
                #pragma unroll
                for (int r = 0; r < 4; ++r) {
                    int nn = (2 * wave + mt) * 16 + lg * 4 + r;
                    float kpv = (m < NB) ? c_ratio * (__expf(xds[mt][nt][r] * c_dn - dg[nn] - mx) + 1e-4f) : 0.f;
                    KpT[m][nn] = f2b(kpv);
                }
            }
        __syncthreads();
        #pragma unroll
        for (int ks = 0; ks < 4; ++ks)
            #pragma unroll
            for (int mt = 0; mt < 2; ++mt) {
                bf16x8 af2 = *(bf16x8*)&KpT[(2 * wave + mt) * 16 + lr][ks * 32 + lg * 8];
                #pragma unroll
                for (int nt = 0; nt < 3; ++nt) {
                    bf16x8 bf2v = *(bf16x8*)&VsT[nt * 16 + lr][ks * 32 + lg * 8];
                    ctxacc[mt][nt] = __builtin_amdgcn_mfma_f32_16x16x32_bf16(af2, bf2v, ctxacc[mt][nt], 0, 0, 0);
                }
            }
        __syncthreads();
    }
    #pragma unroll
    for (int mt = 0; mt < 2; ++mt)
        #pragma unroll
        for (int nt = 0; nt < 3; ++nt)
            #pragma unroll
            for (int r = 0; r < 4; ++r) {
                int m = (2 * wave + mt) * 16 + lg * 4 + r;
                atomicAdd(&ctx[((size_t)bh * 128 + m) * 48 + nt * 16 + lr], ctxacc[mt][nt][r]);
            }
}

// ---------------- og ----------------
__global__ __launch_bounds__(256) void og_kernel(const unsigned short* __restrict__ q,
                                                 const float* __restrict__ proj,
                                                 const float* __restrict__ ctx,
                                                 unsigned short* __restrict__ o) {
    __shared__ __align__(16) char pool[34816];
    unsigned short (*As)[40] = (unsigned short(*)[40])pool;
    unsigned short (*Qp)[136] = (unsigned short(*)[136])pool;
    __shared__ unsigned short Pj[112][40];
    __shared__ unsigned short CsT[48][136];
    __shared__ float dg[128];
    int tid = threadIdx.x;
    int bh = blockIdx.x >> 6, b = bh >> 3, h = bh & 7;
    int n0 = (blockIdx.x & 63) * 128;
    for (int idx = tid; idx < 112 * 8; idx += 256) {
        int m = idx >> 3, f4 = idx & 7;
        if (m < NB) {
            float4 va = *(const float4*)(proj + m * 32 + f4 * 4);
            bf16x4 pk = {(short)f2b(va.x), (short)f2b(va.y), (short)f2b(va.z), (short)f2b(va.w)};
            *(bf16x4*)&Pj[m][f4 * 4] = pk;
        } else {
            *(bf16x4*)&Pj[m][f4 * 4] = (bf16x4){0, 0, 0, 0};
        }
    }
    for (int idx = tid; idx < 128 * 12; idx += 256) {
        int m = idx / 12, c4 = idx - m * 12;
        float4 cv = *(const float4*)(ctx + ((size_t)bh * 128 + m) * 48 + c4 * 4);
        CsT[c4 * 4 + 0][m] = f2b(cv.x);
        CsT[c4 * 4 + 1][m] = f2b(cv.y);
        CsT[c4 * 4 + 2][m] = f2b(cv.z);
        CsT[c4 * 4 + 3][m] = f2b(cv.w);
    }
    int arow = tid >> 1, ahalf = tid & 1;
    {
        const unsigned short* qp_ = q + ((size_t)(b * NSEQ + n0 + arow) * 256 + h * 32 + ahalf * 16);
        bf16x8 q0 = *(const bf16x8*)qp_;
        bf16x8 q1 = *(const bf16x8*)(qp_ + 8);
        *(bf16x8*)&As[arow][ahalf * 16] = q0;
        *(bf16x8*)&As[arow][ahalf * 16 + 8] = q1;
        float ssq = 0.f;
        #pragma unroll
        for (int e = 0; e < 8; ++e) {
            float a = b2f((unsigned short)q0[e]), bb = b2f((unsigned short)q1[e]);
            ssq += a * a + bb * bb;
        }
        ssq += __shfl_xor(ssq, 1);
        if (ahalf == 0) dg[arow] = ssq * c_diagf;
    }
    __syncthreads();
    int wave = tid >> 6, lane = tid & 63, lr = lane & 15, lg = lane >> 4;
    f32x4 xds[2][7];
    #pragma unroll
    for (int mt = 0; mt < 2; ++mt) {
        bf16x8 af = *(bf16x8*)&As[(2 * wave + mt) * 16 + lr][lg * 8];
        #pragma unroll
        for (int nt = 0; nt < 7; ++nt) {
            bf16x8 bfp = *(bf16x8*)&Pj[nt * 16 + lr][lg * 8];
            f32x4 d = (f32x4){0.f, 0.f, 0.f, 0.f};
            xds[mt][nt] = __builtin_amdgcn_mfma_f32_16x16x32_bf16(af, bfp, d, 0, 0, 0);
        }
    }
    float rmax[2][4];
    #pragma unroll
    for (int mt = 0; mt < 2; ++mt)
        #pragma unroll
        for (int r = 0; r < 4; ++r) {
            float mv = -1e30f;
            #pragma unroll
            for (int nt = 0; nt < 7; ++nt)
                if (!(nt == 6 && lr >= 14)) mv = fmaxf(mv, xds[mt][nt][r]);
            mv = fmaxf(mv, __shfl_xor(mv, 1));
            mv = fmaxf(mv, __shfl_xor(mv, 2));
            mv = fmaxf(mv, __shfl_xor(mv, 4));
            mv = fmaxf(mv, __shfl_xor(mv, 8));
            rmax[mt][r] = mv;
        }
    __syncthreads();
    #pragma unroll
    for (int mt = 0; mt < 2; ++mt)
        #pragma unroll
        for (int r = 0; r < 4; ++r) {
            int row = (2 * wave + mt) * 16 + lg * 4 + r;
            #pragma unroll
            for (int nt = 0; nt < 7; ++nt) {
                int m = nt * 16 + lr;
                float qpv = (m < NB)
                    ? c_ratio * (__expf((xds[mt][nt][r] - rmax[mt][r]) * c_dn - dg[row]) + 1e-4f)
                    : 0.f;
                Qp[row][m] = f2b(qpv);
            }
            Qp[row][112 + lr] = 0;
        }
    __syncthreads();
    f32x4 oacc[2][3];
    #pragma unroll
    for (int mt = 0; mt < 2; ++mt)
        #pragma unroll
        for (int nt = 0; nt < 3; ++nt) oacc[mt][nt] = (f32x4){0.f, 0.f, 0.f, 0.f};
    #pragma unroll
    for (int ks = 0; ks < 4; ++ks)
        #pragma unroll
        for (int mt = 0; mt < 2; ++mt) {
            bf16x8 af2 = *(bf16x8*)&Qp[(2 * wave + mt) * 16 + lr][ks * 32 + lg * 8];
            #pragma unroll
            for (int nt = 0; nt < 3; ++nt) {
                bf16x8 bf2v = *(bf16x8*)&CsT[nt * 16 + lr][ks * 32 + lg * 8];
                oacc[mt][nt] = __builtin_amdgcn_mfma_f32_16x16x32_bf16(af2, bf2v, oacc[mt][nt], 0, 0, 0);
            }
        }
    #pragma unroll
    for (int mt = 0; mt < 2; ++mt)
        #pragma unroll
        for (int r = 0; r < 4; ++r) {
            int row = (2 * wave + mt) * 16 + lg * 4 + r;
            int n = n0 + row;
            float den = __shfl(oacc[mt][2][r], lane & 48);
            float inv = 1.0f / den;
            size_t base = (size_t)(b * NSEQ + n) * 256 + h * 32;
            o[base + lr] = f2b(oacc[mt][0][r] * inv);
            o[base + 16 + lr] = f2b(oacc[mt][1][r] * inv);
        }
}

extern "C" void kernel_launch(void* const* d_in, const int* in_sizes, int n_in,
                              void* d_out, int out_size, void* d_ws, size_t ws_size,
                              hipStream_t stream) {
    const float* x = (const float*)d_in[0];
    const float* proj = (const float*)d_in[1];
    const float* ln1_g = (const float*)d_in[2];
    const float* ln1_b = (const float*)d_in[3];
    const float* Wq = (const float*)d_in[4];
    const float* bq = (const float*)d_in[5];
    const float* Wk = (const float*)d_in[6];
    const float* bk = (const float*)d_in[7];
    const float* Wv = (const float*)d_in[8];
    const float* bv = (const float*)d_in[9];
    const float* Wo = (const float*)d_in[10];
    const float* bo = (const float*)d_in[11];
    const float* ln2_g = (const float*)d_in[12];
    const float* ln2_b = (const float*)d_in[13];
    const float* Wf1 = (const float*)d_in[14];
    const float* bf1 = (const float*)d_in[15];
    const float* Wf2 = (const float*)d_in[16];
    const float* bf2 = (const float*)d_in[17];

    float* h = (float*)d_out;
    const size_t ACT = (size_t)MROWS * DIM;
    unsigned short* y = (unsigned short*)d_ws;
    unsigned short* q = y + ACT;
    unsigned short* k = q + ACT;
    unsigned short* v = k + ACT;
    unsigned short* mid = v + ACT;                   // [32768][1024] bf16
    float* ctx = (float*)(mid + 4 * ACT);
    float* kmaxf = ctx + (size_t)BH * 128 * 48;
    float* partial = kmaxf + 32;                     // 2048*8 floats
    float* bqkv = partial + 2048 * 8;                // 4*768 floats
    unsigned short* wt = (unsigned short*)(bqkv + 4 * 768);
    unsigned short* o = y;

    const int WT_L = 786432;
    const int CTXN = BH * 128 * 48;

    copy4_kernel<<<(int)(ACT / 4) / 256, 256, 0, stream>>>((const float4*)x, (float4*)h, (int)(ACT / 4));

    wt_kernel<<<dim3(8, 8, 4), 256, 0, stream>>>(Wq, wt + 0, 256, 256, WT_L);
    wt_kernel<<<dim3(8, 8, 4), 256, 0, stream>>>(Wk, wt + 65536, 256, 256, WT_L);
    wt_kernel<<<dim3(8, 8, 4), 256, 0, stream>>>(Wv, wt + 131072, 256, 256, WT_L);
    wt_kernel<<<dim3(8, 8, 4), 256, 0, stream>>>(Wo, wt + 196608, 256, 256, WT_L);
    wt_kernel<<<dim3(8, 32, 4), 256, 0, stream>>>(Wf1, wt + 262144, 256, 1024, WT_L);
    wt_kernel<<<dim3(32, 8, 4), 256, 0, stream>>>(Wf2, wt + 524288, 1024, 256, WT_L);
    bcat_kernel<<<4, 256, 0, stream>>>(bq, bk, bv, bqkv);

    for (int i = 0; i < 4; ++i) {
        const float* proj_i = proj + (size_t)i * NB * DHEAD;
        const unsigned short* wl = wt + (size_t)i * WT_L;
        // --- attention ---
        ln_kernel<<<MROWS / 4, 256, 0, stream>>>(h, ln1_g + i * DIM, ln1_b + i * DIM, y);
        gemm_mfma<3><<<dim3(6, 256), 256, 0, stream>>>(y, wl + 0, bqkv + i * 768, nullptr, q, 768, DIM);

        zero_kernel<<<(CTXN + 255) / 256, 256, 0, stream>>>(ctx, CTXN);
        kmaxg_kernel<<<2048, 256, 0, stream>>>(k, proj_i, partial);
        kreduce_kernel<<<BH, 256, 0, stream>>>(partial, kmaxf);
        ctxg_kernel<<<dim3(16, BH), 256, 0, stream>>>(k, v, proj_i, kmaxf, ctx);
        og_kernel<<<BH * 64, 256, 0, stream>>>(q, proj_i, ctx, o);

        gemm_mfma<1><<<dim3(2, 256), 256, 0, stream>>>(o, wl + 196608, bo + i * DIM, h, h, DIM, INNER);

        // --- FFN ---
        ln_kernel<<<MROWS / 4, 256, 0, stream>>>(h, ln2_g + i * DIM, ln2_b + i * DIM, y);
        gemm_mfma<2><<<dim3(8, 256), 256, 0, stream>>>(y, wl + 262144, bf1 + i * FFDIM, nullptr, mid, FFDIM, DIM);
        gemm_mfma<1><<<dim3(2, 256), 256, 0, stream>>>(mid, wl + 524288, bf2 + i * DIM, h, h, DIM, FFDIM);
    }
}

// Round 13
// 883.119 us; speedup vs baseline: 1.1860x; 1.0104x over previous
//
#include <hip/hip_runtime.h>
#include <math.h>

#define NSEQ 8192
#define BATCH 4
#define DIM 256
#define HEADS 8
#define DHEAD 32
#define NB 110
#define INNER 256
#define FFDIM 1024
#define MROWS (BATCH * NSEQ)   // 32768 rows
#define BH (BATCH * HEADS)     // 32

typedef __attribute__((ext_vector_type(8))) short bf16x8;
typedef __attribute__((ext_vector_type(4))) short bf16x4;
typedef __attribute__((ext_vector_type(4))) float f32x4;

typedef __attribute__((address_space(1))) const void* gas_cvp;
typedef __attribute__((address_space(3))) void* las_vp;

constexpr float c_dn = 0.42044820762685725f;     // 32^-0.25
constexpr float c_diagf = 0.08838834764831845f;  // 0.5*dn*dn
constexpr float c_ratio = 0.09534625892455922f;  // 110^-0.5

__device__ __forceinline__ unsigned short f2b(float f) {
    unsigned u = __float_as_uint(f);
    unsigned r = (u + 0x7FFFu + ((u >> 16) & 1u)) >> 16;
    return (unsigned short)r;
}
__device__ __forceinline__ float b2f(unsigned short u) {
    return __uint_as_float((unsigned)u << 16);
}

// ---------------- util ----------------
__global__ __launch_bounds__(256) void copy4_kernel(const float4* __restrict__ src,
                                                    float4* __restrict__ dst, int n4) {
    int i = blockIdx.x * 256 + threadIdx.x;
    if (i < n4) dst[i] = src[i];
}
__global__ __launch_bounds__(256) void zero_kernel(float* __restrict__ p, int n) {
    int i = blockIdx.x * 256 + threadIdx.x;
    if (i < n) p[i] = 0.0f;
}
__global__ __launch_bounds__(256) void bcat_kernel(const float* __restrict__ bq,
                                                   const float* __restrict__ bk,
                                                   const float* __restrict__ bv,
                                                   float* __restrict__ out) {
    int l = blockIdx.x, t = threadIdx.x;
    out[l * 768 + t] = bq[l * 256 + t];
    out[l * 768 + 256 + t] = bk[l * 256 + t];
    out[l * 768 + 512 + t] = bv[l * 256 + t];
}

// ---------------- LayerNorm: f32 in -> bf16 out ----------------
__global__ __launch_bounds__(256) void ln_kernel(const float* __restrict__ x,
                                                 const float* __restrict__ g,
                                                 const float* __restrict__ bta,
                                                 unsigned short* __restrict__ y) {
    int wave = threadIdx.x >> 6, lane = threadIdx.x & 63;
    int row = blockIdx.x * 4 + wave;
    const float* xr = x + (size_t)row * DIM;
    float4 v = *(const float4*)(xr + lane * 4);
    float s = v.x + v.y + v.z + v.w;
    float sq = v.x * v.x + v.y * v.y + v.z * v.z + v.w * v.w;
    #pragma unroll
    for (int off = 32; off; off >>= 1) {
        s += __shfl_xor(s, off);
        sq += __shfl_xor(sq, off);
    }
    float mean = s * (1.0f / DIM);
    float var = sq * (1.0f / DIM) - mean * mean;
    float rstd = rsqrtf(var + 1e-5f);
    float4 gg = *(const float4*)(g + lane * 4);
    float4 bb = *(const float4*)(bta + lane * 4);
    bf16x4 o;
    o[0] = (short)f2b((v.x - mean) * rstd * gg.x + bb.x);
    o[1] = (short)f2b((v.y - mean) * rstd * gg.y + bb.y);
    o[2] = (short)f2b((v.z - mean) * rstd * gg.z + bb.z);
    o[3] = (short)f2b((v.w - mean) * rstd * gg.w + bb.w);
    *(bf16x4*)(y + (size_t)row * DIM + lane * 4) = o;
}

// ---------------- weight transpose+convert: out[l][n][k] = bf16(in[l][k][n]) ----------------
__global__ __launch_bounds__(256) void wt_kernel(const float* __restrict__ in,
                                                 unsigned short* __restrict__ out,
                                                 int K, int Nn, int lstride) {
    __shared__ float t32[32][33];
    int l = blockIdx.z;
    const float* inp = in + (size_t)l * K * Nn;
    unsigned short* outp = out + (size_t)l * lstride;
    int k0 = blockIdx.x * 32, n0 = blockIdx.y * 32;
    int tx = threadIdx.x & 31, ty = threadIdx.x >> 5;
    #pragma unroll
    for (int i = 0; i < 4; ++i)
        t32[ty + i * 8][tx] = inp[(size_t)(k0 + ty + i * 8) * Nn + n0 + tx];
    __syncthreads();
    #pragma unroll
    for (int i = 0; i < 4; ++i) {
        int r = ty + i * 8;  // n within tile
        outp[(size_t)(n0 + r) * K + k0 + tx] = f2b(t32[tx][r]);
    }
}

// ---------------- bf16 MFMA GEMM, 3-buffer (2-ahead) global_load_lds pipeline ----------------
// EPI 0: +bias -> bf16   EPI 1: +bias+res(f32) -> f32   EPI 2: gelu(+bias) -> bf16
// EPI 3: +bias -> bf16 segmented (col>>8 selects q/k/v plane of stride MROWS*DIM)
// Pipeline: prologue stages tiles 0,1; iter kt stages kt+2 then waits vmcnt(8) (tile kt's
// 4 loads retired; kt+1/kt+2's 8 may remain in flight). Tail ramps vmcnt 4 -> 0.
// Tile kt+3 reuses buffer kt%3, staged at iter kt+1 AFTER iter kt's end barrier (safe).
template <int EPI>
__global__ __launch_bounds__(256) void gemm_mfma(const unsigned short* __restrict__ A,
                                                 const unsigned short* __restrict__ Wt,
                                                 const float* __restrict__ bias,
                                                 const float* __restrict__ res,
                                                 void* __restrict__ Cv,
                                                 int Nn, int K) {
    __shared__ __align__(16) unsigned short pool[24576];   // As[3][4096] | Bs[3][4096]; C-tile reuses [0,16384)
    unsigned short* AsP = pool;           // + buf*4096
    unsigned short* BsP = pool + 12288;   // + buf*4096
    int tid = threadIdx.x;
    int m0 = blockIdx.y * 128, n0 = blockIdx.x * 128;
    int wave = tid >> 6, lane = tid & 63;
    int wm = (wave >> 1) * 64, wn = (wave & 1) * 64;
    int lr = lane & 15, lg = lane >> 4;
    f32x4 acc[4][4];
    #pragma unroll
    for (int i = 0; i < 4; ++i)
        #pragma unroll
        for (int j = 0; j < 4; ++j) acc[i][j] = (f32x4){0.f, 0.f, 0.f, 0.f};

    int rowS[2], chS[2];
    #pragma unroll
    for (int j = 0; j < 2; ++j) {
        int f = wave * 128 + j * 64 + lane;
        rowS[j] = f >> 2;
        chS[j] = ((f & 3) ^ ((rowS[j] >> 1) & 3)) * 8;
    }
    int rdA[4], rdB[4];
    #pragma unroll
    for (int i = 0; i < 4; ++i) {
        int ra = wm + i * 16 + lr;
        rdA[i] = ra * 32 + (lg ^ ((ra >> 1) & 3)) * 8;
        int rb = wn + i * 16 + lr;
        rdB[i] = rb * 32 + (lg ^ ((rb >> 1) & 3)) * 8;
    }

    const int NT = K >> 5;
    // prologue: stage tiles 0 and 1
    #pragma unroll
    for (int t = 0; t < 2; ++t) {
        #pragma unroll
        for (int j = 0; j < 2; ++j) {
            const unsigned short* srcA = A + (size_t)(m0 + rowS[j]) * K + t * 32 + chS[j];
            __builtin_amdgcn_global_load_lds((gas_cvp)srcA,
                                             (las_vp)(AsP + t * 4096 + wave * 1024 + j * 512), 16, 0, 0);
            const unsigned short* srcB = Wt + (size_t)(n0 + rowS[j]) * K + t * 32 + chS[j];
            __builtin_amdgcn_global_load_lds((gas_cvp)srcB,
                                             (las_vp)(BsP + t * 4096 + wave * 1024 + j * 512), 16, 0, 0);
        }
    }
    int buf = 0;
    for (int kt = 0; kt < NT; ++kt) {
        if (kt + 2 < NT) {
            int nb = (kt + 2) % 3;
            int koff = (kt + 2) * 32;
            #pragma unroll
            for (int j = 0; j < 2; ++j) {
                const unsigned short* srcA = A + (size_t)(m0 + rowS[j]) * K + koff + chS[j];
                __builtin_amdgcn_global_load_lds((gas_cvp)srcA,
                                                 (las_vp)(AsP + nb * 4096 + wave * 1024 + j * 512), 16, 0, 0);
                const unsigned short* srcB = Wt + (size_t)(n0 + rowS[j]) * K + koff + chS[j];
                __builtin_amdgcn_global_load_lds((gas_cvp)srcB,
                                                 (las_vp)(BsP + nb * 4096 + wave * 1024 + j * 512), 16, 0, 0);
            }
        }
        int ahead = NT - 1 - kt;
        if (ahead >= 2)      asm volatile("s_waitcnt vmcnt(8)" ::: "memory");
        else if (ahead == 1) asm volatile("s_waitcnt vmcnt(4)" ::: "memory");
        else                 asm volatile("s_waitcnt vmcnt(0)" ::: "memory");
        __builtin_amdgcn_s_barrier();
        __builtin_amdgcn_sched_barrier(0);
        bf16x8 af[4], bfv[4];
        #pragma unroll
        for (int i = 0; i < 4; ++i) af[i] = *(bf16x8*)&AsP[buf * 4096 + rdA[i]];
        #pragma unroll
        for (int j = 0; j < 4; ++j) bfv[j] = *(bf16x8*)&BsP[buf * 4096 + rdB[j]];
        #pragma unroll
        for (int i = 0; i < 4; ++i)
            #pragma unroll
            for (int j = 0; j < 4; ++j)
                acc[i][j] = __builtin_amdgcn_mfma_f32_16x16x32_bf16(af[i], bfv[j], acc[i][j], 0, 0, 0);
        __builtin_amdgcn_sched_barrier(0);
        __builtin_amdgcn_s_barrier();
        buf = (buf + 1 == 3) ? 0 : buf + 1;
    }

    if (EPI == 1) {
        // scalar f32 epilogue (+bias+res)
        #pragma unroll
        for (int i = 0; i < 4; ++i) {
            #pragma unroll
            for (int j = 0; j < 4; ++j) {
                int col = n0 + wn + j * 16 + lr;
                float bv = bias[col];
                #pragma unroll
                for (int r = 0; r < 4; ++r) {
                    int row = m0 + wm + i * 16 + lg * 4 + r;
                    float c = acc[i][j][r] + bv + res[(size_t)row * Nn + col];
                    ((float*)Cv)[(size_t)row * Nn + col] = c;
                }
            }
        }
    } else {
        // LDS-transposed bf16 epilogue: pool[0,16384) becomes C[128][128] bf16, granule-swizzled.
        #pragma unroll
        for (int i = 0; i < 4; ++i) {
            #pragma unroll
            for (int j = 0; j < 4; ++j) {
                int tcol = wn + j * 16 + lr;
                float bv = bias[n0 + tcol];
                #pragma unroll
                for (int r = 0; r < 4; ++r) {
                    int trow = wm + i * 16 + lg * 4 + r;
                    float c = acc[i][j][r] + bv;
                    if (EPI == 2) {
                        float u = c;
                        float t = 1.5957691216057308f * (u + 0.044715f * u * u * u);
                        c = u / (1.0f + __expf(-t));
                    }
                    pool[trow * 128 + (((tcol >> 3) ^ (trow & 7)) << 3) + (tcol & 7)] = f2b(c);
                }
            }
        }
        __syncthreads();
        #pragma unroll
        for (int cch = 0; cch < 8; ++cch) {
            int g = cch * 256 + tid;          // granule id: 2048 = 128 rows x 16 chunks
            int row = g >> 4, cc = g & 15;
            bf16x8 val = *(bf16x8*)&pool[row * 128 + ((cc ^ (row & 7)) << 3)];
            int grow = m0 + row;
            int gcol = n0 + cc * 8;
            if (EPI == 3) {
                size_t idx = (size_t)(gcol >> 8) * ((size_t)MROWS * DIM) + (size_t)grow * 256 + (gcol & 255);
                *(bf16x8*)((unsigned short*)Cv + idx) = val;
            } else {
                *(bf16x8*)((unsigned short*)Cv + (size_t)grow * Nn + gcol) = val;
            }
        }
    }
}

// ---------------- kmaxg ----------------
__global__ __launch_bounds__(256) void kmaxg_kernel(const unsigned short* __restrict__ k,
                                                    const float* __restrict__ proj,
                                                    float* __restrict__ partial) {
    __shared__ unsigned short As[128][40];
    __shared__ unsigned short Pj[112][40];
    __shared__ float wmax[4][8];
    int tid = threadIdx.x;
    int r0 = blockIdx.x * 128;
    for (int idx = tid; idx < 112 * 8; idx += 256) {
        int m = idx >> 3, f4 = idx & 7;
        if (m < NB) {
            float4 va = *(const float4*)(proj + m * 32 + f4 * 4);
            bf16x4 pk = {(short)f2b(va.x), (short)f2b(va.y), (short)f2b(va.z), (short)f2b(va.w)};
            *(bf16x4*)&Pj[m][f4 * 4] = pk;
        } else {
            *(bf16x4*)&Pj[m][f4 * 4] = (bf16x4){0, 0, 0, 0};
        }
    }
    int arow = tid >> 1, ahalf = tid & 1;
    const unsigned short* ap = k + (size_t)(r0 + arow) * 32 + ahalf * 16;
    *(bf16x8*)&As[arow][ahalf * 16] = *(const bf16x8*)ap;
    *(bf16x8*)&As[arow][ahalf * 16 + 8] = *(const bf16x8*)(ap + 8);
    __syncthreads();
    int wave = tid >> 6, lane = tid & 63, lr = lane & 15, lg = lane >> 4;
    float mymax[4] = {-1e30f, -1e30f, -1e30f, -1e30f};
    #pragma unroll
    for (int mt = 0; mt < 2; ++mt) {
        bf16x8 af = *(bf16x8*)&As[(2 * wave + mt) * 16 + lr][lg * 8];
        #pragma unroll
        for (int nt = 0; nt < 7; ++nt) {
            bf16x8 bfp = *(bf16x8*)&Pj[nt * 16 + lr][lg * 8];
            f32x4 d = (f32x4){0.f, 0.f, 0.f, 0.f};
            d = __builtin_amdgcn_mfma_f32_16x16x32_bf16(af, bfp, d, 0, 0, 0);
            if (!(nt == 6 && lr >= 14)) {
                #pragma unroll
                for (int r = 0; r < 4; ++r) mymax[r] = fmaxf(mymax[r], d[r]);
            }
        }
    }
    #pragma unroll
    for (int r = 0; r < 4; ++r) {
        float v = mymax[r];
        v = fmaxf(v, __shfl_xor(v, 1));
        v = fmaxf(v, __shfl_xor(v, 2));
        v = fmaxf(v, __shfl_xor(v, 4));
        v = fmaxf(v, __shfl_xor(v, 8));
        v = fmaxf(v, __shfl_xor(v, 32));
        mymax[r] = v;
    }
    if (lane == 0 || lane == 16) {
        int hb = (lane >> 4) & 1;
        #pragma unroll
        for (int r = 0; r < 4; ++r) wmax[wave][4 * hb + r] = mymax[r];
    }
    __syncthreads();
    if (tid < 8) {
        float m = fmaxf(fmaxf(wmax[0][tid], wmax[1][tid]), fmaxf(wmax[2][tid], wmax[3][tid]));
        partial[blockIdx.x * 8 + tid] = m * c_dn;
    }
}

// ---------------- kreduce ----------------
__global__ __launch_bounds__(256) void kreduce_kernel(const float* __restrict__ partial,
                                                      float* __restrict__ kmaxf) {
    __shared__ float wred[4];
    int bh = blockIdx.x, b = bh >> 3, h = bh & 7;
    int tid = threadIdx.x;
    float m = fmaxf(partial[(b * 512 + tid) * 8 + h], partial[(b * 512 + 256 + tid) * 8 + h]);
    #pragma unroll
    for (int off = 32; off; off >>= 1) m = fmaxf(m, __shfl_xor(m, off));
    if ((tid & 63) == 0) wred[tid >> 6] = m;
    __syncthreads();
    if (tid == 0)
        kmaxf[bh] = fmaxf(fmaxf(wred[0], wred[1]), fmaxf(wred[2], wred[3]));
}

// ---------------- ctxg ----------------
__global__ __launch_bounds__(256) void ctxg_kernel(const unsigned short* __restrict__ k,
                                                   const unsigned short* __restrict__ v,
                                                   const float* __restrict__ proj,
                                                   const float* __restrict__ kmaxf,
                                                   float* __restrict__ ctx) {
    __shared__ __align__(16) char pool[34816];
    unsigned short (*As)[40] = (unsigned short(*)[40])pool;
    unsigned short (*KpT)[136] = (unsigned short(*)[136])pool;
    __shared__ unsigned short Pj[112][40];
    __shared__ unsigned short VsT[48][136];
    __shared__ float dg[128];
    int tid = threadIdx.x;
    int bh = blockIdx.y, b = bh >> 3, h = bh & 7;
    int n_base = blockIdx.x * 512;
    float mx = kmaxf[bh];
    for (int idx = tid; idx < 112 * 8; idx += 256) {
        int m = idx >> 3, f4 = idx & 7;
        if (m < NB) {
            float4 va = *(const float4*)(proj + m * 32 + f4 * 4);
            bf16x4 pk = {(short)f2b(va.x), (short)f2b(va.y), (short)f2b(va.z), (short)f2b(va.w)};
            *(bf16x4*)&Pj[m][f4 * 4] = pk;
        } else {
            *(bf16x4*)&Pj[m][f4 * 4] = (bf16x4){0, 0, 0, 0};
        }
    }
    for (int idx = tid; idx < 16 * 136; idx += 256) KpT[112 + idx / 136][idx % 136] = 0;
    for (int idx = tid; idx < 16 * 128; idx += 256) {
        int rr = 32 + (idx >> 7), nn = idx & 127;
        VsT[rr][nn] = (rr == 32) ? (unsigned short)0x3F80 : (unsigned short)0;
    }
    int wave = tid >> 6, lane = tid & 63, lr = lane & 15, lg = lane >> 4;
    int arow = tid >> 1, ahalf = tid & 1;
    f32x4 ctxacc[2][3];
    #pragma unroll
    for (int mt = 0; mt < 2; ++mt)
        #pragma unroll
        for (int nt = 0; nt < 3; ++nt) ctxacc[mt][nt] = (f32x4){0.f, 0.f, 0.f, 0.f};

    for (int ni = 0; ni < 4; ++ni) {
        int n0 = n_base + ni * 128;
        {
            const unsigned short* kp_ = k + ((size_t)(b * NSEQ + n0 + arow) * 256 + h * 32 + ahalf * 16);
            bf16x8 k0 = *(const bf16x8*)kp_;
            bf16x8 k1 = *(const bf16x8*)(kp_ + 8);
            *(bf16x8*)&As[arow][ahalf * 16] = k0;
            *(bf16x8*)&As[arow][ahalf * 16 + 8] = k1;
            float ssq = 0.f;
            #pragma unroll
            for (int e = 0; e < 8; ++e) {
                float a = b2f((unsigned short)k0[e]), bb = b2f((unsigned short)k1[e]);
                ssq += a * a + bb * bb;
            }
            ssq += __shfl_xor(ssq, 1);
            if (ahalf == 0) dg[arow] = ssq * c_diagf;
        }
        #pragma unroll
        for (int it = 0; it < 4; ++it) {
            int idx = it * 256 + tid;
            int nn = idx >> 3, f4 = idx & 7;
            bf16x4 vv = *(const bf16x4*)(v + ((size_t)(b * NSEQ + n0 + nn) * 256 + h * 32 + f4 * 4));
            VsT[f4 * 4 + 0][nn] = (unsigned short)vv[0];
            VsT[f4 * 4 + 1][nn] = (unsigned short)vv[1];
            VsT[f4 * 4 + 2][nn] = (unsigned short)vv[2];
            VsT[f4 * 4 + 3][nn] = (unsigned short)vv[3];
        }
        __syncthreads();
        f32x4 xds[2][7];
        #pragma unroll
        for (int mt = 0; mt < 2; ++mt) {
            bf16x8 af = *(bf16x8*)&As[(2 * wave + mt) * 16 + lr][lg * 8];
            #pragma unroll
            for (int nt = 0; nt < 7; ++nt) {
                bf16x8 bfp = *(bf16x8*)&Pj[nt * 16 + lr][lg * 8];
                f32x4 d = (f32x4){0.f, 0.f, 0.f, 0.f};
                xds[mt][nt] = __builtin_amdgcn_mfma_f32_16x16x32_bf16(af, bfp, d, 0, 0, 0);
            }
        }
        __syncthreads();
        #pragma unroll
        for (int mt = 0; mt < 2; ++mt)
            #pragma unroll
            for (int nt = 0; nt < 7; ++nt) {
                int m = nt * 16 + lr;
                #pragma unroll
                for (int r = 0; r < 4; ++r) {
                    int nn = (2 * wave + mt) * 16 + lg * 4 + r;
                    float kpv = (m < NB) ? c_ratio * (__expf(xds[mt][nt][r] * c_dn - dg[nn] - mx) + 1e-4f) : 0.f;
                    KpT[m][nn] = f2b(kpv);
                }
            }
        __syncthreads();
        #pragma unroll
        for (int ks = 0; ks < 4; ++ks)
            #pragma unroll
            for (int mt = 0; mt < 2; ++mt) {
                bf16x8 af2 = *(bf16x8*)&KpT[(2 * wave + mt) * 16 + lr][ks * 32 + lg * 8];
                #pragma unroll
                for (int nt = 0; nt < 3; ++nt) {
                    bf16x8 bf2v = *(bf16x8*)&VsT[nt * 16 + lr][ks * 32 + lg * 8];
                    ctxacc[mt][nt] = __builtin_amdgcn_mfma_f32_16x16x32_bf16(af2, bf2v, ctxacc[mt][nt], 0, 0, 0);
                }
            }
        __syncthreads();
    }
    #pragma unroll
    for (int mt = 0; mt < 2; ++mt)
        #pragma unroll
        for (int nt = 0; nt < 3; ++nt)
            #pragma unroll
            for (int r = 0; r < 4; ++r) {
                int m = (2 * wave + mt) * 16 + lg * 4 + r;
                atomicAdd(&ctx[((size_t)bh * 128 + m) * 48 + nt * 16 + lr], ctxacc[mt][nt][r]);
            }
}

// ---------------- og ----------------
__global__ __launch_bounds__(256) void og_kernel(const unsigned short* __restrict__ q,
                                                 const float* __restrict__ proj,
                                                 const float* __restrict__ ctx,
                                                 unsigned short* __restrict__ o) {
    __shared__ __align__(16) char pool[34816];
    unsigned short (*As)[40] = (unsigned short(*)[40])pool;
    unsigned short (*Qp)[136] = (unsigned short(*)[136])pool;
    __shared__ unsigned short Pj[112][40];
    __shared__ unsigned short CsT[48][136];
    __shared__ float dg[128];
    int tid = threadIdx.x;
    int bh = blockIdx.x >> 6, b = bh >> 3, h = bh & 7;
    int n0 = (blockIdx.x & 63) * 128;
    for (int idx = tid; idx < 112 * 8; idx += 256) {
        int m = idx >> 3, f4 = idx & 7;
        if (m < NB) {
            float4 va = *(const float4*)(proj + m * 32 + f4 * 4);
            bf16x4 pk = {(short)f2b(va.x), (short)f2b(va.y), (short)f2b(va.z), (short)f2b(va.w)};
            *(bf16x4*)&Pj[m][f4 * 4] = pk;
        } else {
            *(bf16x4*)&Pj[m][f4 * 4] = (bf16x4){0, 0, 0, 0};
        }
    }
    for (int idx = tid; idx < 128 * 12; idx += 256) {
        int m = idx / 12, c4 = idx - m * 12;
        float4 cv = *(const float4*)(ctx + ((size_t)bh * 128 + m) * 48 + c4 * 4);
        CsT[c4 * 4 + 0][m] = f2b(cv.x);
        CsT[c4 * 4 + 1][m] = f2b(cv.y);
        CsT[c4 * 4 + 2][m] = f2b(cv.z);
        CsT[c4 * 4 + 3][m] = f2b(cv.w);
    }
    int arow = tid >> 1, ahalf = tid & 1;
    {
        const unsigned short* qp_ = q + ((size_t)(b * NSEQ + n0 + arow) * 256 + h * 32 + ahalf * 16);
        bf16x8 q0 = *(const bf16x8*)qp_;
        bf16x8 q1 = *(const bf16x8*)(qp_ + 8);
        *(bf16x8*)&As[arow][ahalf * 16] = q0;
        *(bf16x8*)&As[arow][ahalf * 16 + 8] = q1;
        float ssq = 0.f;
        #pragma unroll
        for (int e = 0; e < 8; ++e) {
            float a = b2f((unsigned short)q0[e]), bb = b2f((unsigned short)q1[e]);
            ssq += a * a + bb * bb;
        }
        ssq += __shfl_xor(ssq, 1);
        if (ahalf == 0) dg[arow] = ssq * c_diagf;
    }
    __syncthreads();
    int wave = tid >> 6, lane = tid & 63, lr = lane & 15, lg = lane >> 4;
    f32x4 xds[2][7];
    #pragma unroll
    for (int mt = 0; mt < 2; ++mt) {
        bf16x8 af = *(bf16x8*)&As[(2 * wave + mt) * 16 + lr][lg * 8];
        #pragma unroll
        for (int nt = 0; nt < 7; ++nt) {
            bf16x8 bfp = *(bf16x8*)&Pj[nt * 16 + lr][lg * 8];
            f32x4 d = (f32x4){0.f, 0.f, 0.f, 0.f};
            xds[mt][nt] = __builtin_amdgcn_mfma_f32_16x16x32_bf16(af, bfp, d, 0, 0, 0);
        }
    }
    float rmax[2][4];
    #pragma unroll
    for (int mt = 0; mt < 2; ++mt)
        #pragma unroll
        for (int r = 0; r < 4; ++r) {
            float mv = -1e30f;
            #pragma unroll
            for (int nt = 0; nt < 7; ++nt)
                if (!(nt == 6 && lr >= 14)) mv = fmaxf(mv, xds[mt][nt][r]);
            mv = fmaxf(mv, __shfl_xor(mv, 1));
            mv = fmaxf(mv, __shfl_xor(mv, 2));
            mv = fmaxf(mv, __shfl_xor(mv, 4));
            mv = fmaxf(mv, __shfl_xor(mv, 8));
            rmax[mt][r] = mv;
        }
    __syncthreads();
    #pragma unroll
    for (int mt = 0; mt < 2; ++mt)
        #pragma unroll
        for (int r = 0; r < 4; ++r) {
            int row = (2 * wave + mt) * 16 + lg * 4 + r;
            #pragma unroll
            for (int nt = 0; nt < 7; ++nt) {
                int m = nt * 16 + lr;
                float qpv = (m < NB)
                    ? c_ratio * (__expf((xds[mt][nt][r] - rmax[mt][r]) * c_dn - dg[row]) + 1e-4f)
                    : 0.f;
                Qp[row][m] = f2b(qpv);
            }
            Qp[row][112 + lr] = 0;
        }
    __syncthreads();
    f32x4 oacc[2][3];
    #pragma unroll
    for (int mt = 0; mt < 2; ++mt)
        #pragma unroll
        for (int nt = 0; nt < 3; ++nt) oacc[mt][nt] = (f32x4){0.f, 0.f, 0.f, 0.f};
    #pragma unroll
    for (int ks = 0; ks < 4; ++ks)
        #pragma unroll
        for (int mt = 0; mt < 2; ++mt) {
            bf16x8 af2 = *(bf16x8*)&Qp[(2 * wave + mt) * 16 + lr][ks * 32 + lg * 8];
            #pragma unroll
            for (int nt = 0; nt < 3; ++nt) {
                bf16x8 bf2v = *(bf16x8*)&CsT[nt * 16 + lr][ks * 32 + lg * 8];
                oacc[mt][nt] = __builtin_amdgcn_mfma_f32_16x16x32_bf16(af2, bf2v, oacc[mt][nt], 0, 0, 0);
            }
        }
    #pragma unroll
    for (int mt = 0; mt < 2; ++mt)
        #pragma unroll
        for (int r = 0; r < 4; ++r) {
            int row = (2 * wave + mt) * 16 + lg * 4 + r;
            int n = n0 + row;
            float den = __shfl(oacc[mt][2][r], lane & 48);
            float inv = 1.0f / den;
            size_t base = (size_t)(b * NSEQ + n) * 256 + h * 32;
            o[base + lr] = f2b(oacc[mt][0][r] * inv);
            o[base + 16 + lr] = f2b(oacc[mt][1][r] * inv);
        }
}

extern "C" void kernel_launch(void* const* d_in, const int* in_sizes, int n_in,
                              void* d_out, int out_size, void* d_ws, size_t ws_size,
                              hipStream_t stream) {
    const float* x = (const float*)d_in[0];
    const float* proj = (const float*)d_in[1];
    const float* ln1_g = (const float*)d_in[2];
    const float* ln1_b = (const float*)d_in[3];
    const float* Wq = (const float*)d_in[4];
    const float* bq = (const float*)d_in[5];
    const float* Wk = (const float*)d_in[6];
    const float* bk = (const float*)d_in[7];
    const float* Wv = (const float*)d_in[8];
    const float* bv = (const float*)d_in[9];
    const float* Wo = (const float*)d_in[10];
    const float* bo = (const float*)d_in[11];
    const float* ln2_g = (const float*)d_in[12];
    const float* ln2_b = (const float*)d_in[13];
    const float* Wf1 = (const float*)d_in[14];
    const float* bf1 = (const float*)d_in[15];
    const float* Wf2 = (const float*)d_in[16];
    const float* bf2 = (const float*)d_in[17];

    float* h = (float*)d_out;
    const size_t ACT = (size_t)MROWS * DIM;
    unsigned short* y = (unsigned short*)d_ws;
    unsigned short* q = y + ACT;
    unsigned short* k = q + ACT;
    unsigned short* v = k + ACT;
    unsigned short* mid = v + ACT;                   // [32768][1024] bf16
    float* ctx = (float*)(mid + 4 * ACT);
    float* kmaxf = ctx + (size_t)BH * 128 * 48;
    float* partial = kmaxf + 32;                     // 2048*8 floats
    float* bqkv = partial + 2048 * 8;                // 4*768 floats
    unsigned short* wt = (unsigned short*)(bqkv + 4 * 768);
    unsigned short* o = y;

    const int WT_L = 786432;
    const int CTXN = BH * 128 * 48;

    copy4_kernel<<<(int)(ACT / 4) / 256, 256, 0, stream>>>((const float4*)x, (float4*)h, (int)(ACT / 4));

    wt_kernel<<<dim3(8, 8, 4), 256, 0, stream>>>(Wq, wt + 0, 256, 256, WT_L);
    wt_kernel<<<dim3(8, 8, 4), 256, 0, stream>>>(Wk, wt + 65536, 256, 256, WT_L);
    wt_kernel<<<dim3(8, 8, 4), 256, 0, stream>>>(Wv, wt + 131072, 256, 256, WT_L);
    wt_kernel<<<dim3(8, 8, 4), 256, 0, stream>>>(Wo, wt + 196608, 256, 256, WT_L);
    wt_kernel<<<dim3(8, 32, 4), 256, 0, stream>>>(Wf1, wt + 262144, 256, 1024, WT_L);
    wt_kernel<<<dim3(32, 8, 4), 256, 0, stream>>>(Wf2, wt + 524288, 1024, 256, WT_L);
    bcat_kernel<<<4, 256, 0, stream>>>(bq, bk, bv, bqkv);

    for (int i = 0; i < 4; ++i) {
        const float* proj_i = proj + (size_t)i * NB * DHEAD;
        const unsigned short* wl = wt + (size_t)i * WT_L;
        // --- attention ---
        ln_kernel<<<MROWS / 4, 256, 0, stream>>>(h, ln1_g + i * DIM, ln1_b + i * DIM, y);
        gemm_mfma<3><<<dim3(6, 256), 256, 0, stream>>>(y, wl + 0, bqkv + i * 768, nullptr, q, 768, DIM);

        zero_kernel<<<(CTXN + 255) / 256, 256, 0, stream>>>(ctx, CTXN);
        kmaxg_kernel<<<2048, 256, 0, stream>>>(k, proj_i, partial);
        kreduce_kernel<<<BH, 256, 0, stream>>>(partial, kmaxf);
        ctxg_kernel<<<dim3(16, BH), 256, 0, stream>>>(k, v, proj_i, kmaxf, ctx);
        og_kernel<<<BH * 64, 256, 0, stream>>>(q, proj_i, ctx, o);

        gemm_mfma<1><<<dim3(2, 256), 256, 0, stream>>>(o, wl + 196608, bo + i * DIM, h, h, DIM, INNER);

        // --- FFN ---
        ln_kernel<<<MROWS / 4, 256, 0, stream>>>(h, ln2_g + i * DIM, ln2_b + i * DIM, y);
        gemm_mfma<2><<<dim3(8, 256), 256, 0, stream>>>(y, wl + 262144, bf1 + i * FFDIM, nullptr, mid, FFDIM, DIM);
        gemm_mfma<1><<<dim3(2, 256), 256, 0, stream>>>(mid, wl + 524288, bf2 + i * DIM, h, h, DIM, FFDIM);
    }
}

// Round 14
// 848.557 us; speedup vs baseline: 1.2343x; 1.0407x over previous
//
#include <hip/hip_runtime.h>
#include <math.h>

#define NSEQ 8192
#define BATCH 4
#define DIM 256
#define HEADS 8
#define DHEAD 32
#define NB 110
#define INNER 256
#define FFDIM 1024
#define MROWS (BATCH * NSEQ)   // 32768 rows
#define BH (BATCH * HEADS)     // 32

typedef __attribute__((ext_vector_type(8))) short bf16x8;
typedef __attribute__((ext_vector_type(4))) short bf16x4;
typedef __attribute__((ext_vector_type(4))) float f32x4;

typedef __attribute__((address_space(1))) const void* gas_cvp;
typedef __attribute__((address_space(3))) void* las_vp;

constexpr float c_dn = 0.42044820762685725f;     // 32^-0.25
constexpr float c_diagf = 0.08838834764831845f;  // 0.5*dn*dn
constexpr float c_ratio = 0.09534625892455922f;  // 110^-0.5

__device__ __forceinline__ unsigned short f2b(float f) {
    unsigned u = __float_as_uint(f);
    unsigned r = (u + 0x7FFFu + ((u >> 16) & 1u)) >> 16;
    return (unsigned short)r;
}
__device__ __forceinline__ float b2f(unsigned short u) {
    return __uint_as_float((unsigned)u << 16);
}

// ---------------- util ----------------
__global__ __launch_bounds__(256) void copy4_kernel(const float4* __restrict__ src,
                                                    float4* __restrict__ dst, int n4) {
    int i = blockIdx.x * 256 + threadIdx.x;
    if (i < n4) dst[i] = src[i];
}
__global__ __launch_bounds__(256) void zero_kernel(float* __restrict__ p, int n) {
    int i = blockIdx.x * 256 + threadIdx.x;
    if (i < n) p[i] = 0.0f;
}
__global__ __launch_bounds__(256) void bcat_kernel(const float* __restrict__ bq,
                                                   const float* __restrict__ bk,
                                                   const float* __restrict__ bv,
                                                   float* __restrict__ out) {
    int l = blockIdx.x, t = threadIdx.x;
    out[l * 768 + t] = bq[l * 256 + t];
    out[l * 768 + 256 + t] = bk[l * 256 + t];
    out[l * 768 + 512 + t] = bv[l * 256 + t];
}

// ---------------- LayerNorm: f32 in -> bf16 out ----------------
__global__ __launch_bounds__(256) void ln_kernel(const float* __restrict__ x,
                                                 const float* __restrict__ g,
                                                 const float* __restrict__ bta,
                                                 unsigned short* __restrict__ y) {
    int wave = threadIdx.x >> 6, lane = threadIdx.x & 63;
    int row = blockIdx.x * 4 + wave;
    const float* xr = x + (size_t)row * DIM;
    float4 v = *(const float4*)(xr + lane * 4);
    float s = v.x + v.y + v.z + v.w;
    float sq = v.x * v.x + v.y * v.y + v.z * v.z + v.w * v.w;
    #pragma unroll
    for (int off = 32; off; off >>= 1) {
        s += __shfl_xor(s, off);
        sq += __shfl_xor(sq, off);
    }
    float mean = s * (1.0f / DIM);
    float var = sq * (1.0f / DIM) - mean * mean;
    float rstd = rsqrtf(var + 1e-5f);
    float4 gg = *(const float4*)(g + lane * 4);
    float4 bb = *(const float4*)(bta + lane * 4);
    bf16x4 o;
    o[0] = (short)f2b((v.x - mean) * rstd * gg.x + bb.x);
    o[1] = (short)f2b((v.y - mean) * rstd * gg.y + bb.y);
    o[2] = (short)f2b((v.z - mean) * rstd * gg.z + bb.z);
    o[3] = (short)f2b((v.w - mean) * rstd * gg.w + bb.w);
    *(bf16x4*)(y + (size_t)row * DIM + lane * 4) = o;
}

// ---------------- weight transpose+convert: out[l][n][k] = bf16(in[l][k][n]) ----------------
__global__ __launch_bounds__(256) void wt_kernel(const float* __restrict__ in,
                                                 unsigned short* __restrict__ out,
                                                 int K, int Nn, int lstride) {
    __shared__ float t32[32][33];
    int l = blockIdx.z;
    const float* inp = in + (size_t)l * K * Nn;
    unsigned short* outp = out + (size_t)l * lstride;
    int k0 = blockIdx.x * 32, n0 = blockIdx.y * 32;
    int tx = threadIdx.x & 31, ty = threadIdx.x >> 5;
    #pragma unroll
    for (int i = 0; i < 4; ++i)
        t32[ty + i * 8][tx] = inp[(size_t)(k0 + ty + i * 8) * Nn + n0 + tx];
    __syncthreads();
    #pragma unroll
    for (int i = 0; i < 4; ++i) {
        int r = ty + i * 8;  // n within tile
        outp[(size_t)(n0 + r) * K + k0 + tx] = f2b(t32[tx][r]);
    }
}

// ---------------- bf16 MFMA GEMM, 3-buffer pipeline + XCD-aware block swizzle ----------------
// EPI 0: +bias -> bf16   EPI 1: +bias+res(f32) -> f32   EPI 2: gelu(+bias) -> bf16
// EPI 3: +bias -> bf16 segmented (col>>8 selects q/k/v plane of stride MROWS*DIM)
// XCD swizzle (T1): consecutive dispatch ids round-robin XCDs; remap so each XCD owns a
// contiguous chunk of (m,n) space -> A-panels hit its private L2 instead of 8x HBM re-fetch.
// Requires nwg % 8 == 0 (all call sites: 1536/512/2048/512).
template <int EPI>
__global__ __launch_bounds__(256) void gemm_mfma(const unsigned short* __restrict__ A,
                                                 const unsigned short* __restrict__ Wt,
                                                 const float* __restrict__ bias,
                                                 const float* __restrict__ res,
                                                 void* __restrict__ Cv,
                                                 int Nn, int K) {
    __shared__ __align__(16) unsigned short pool[24576];   // As[3][4096] | Bs[3][4096]; C-tile reuses [0,16384)
    unsigned short* AsP = pool;           // + buf*4096
    unsigned short* BsP = pool + 12288;   // + buf*4096
    int tid = threadIdx.x;
    int nwg = gridDim.x * gridDim.y;
    int orig = blockIdx.y * gridDim.x + blockIdx.x;
    int swz = (orig & 7) * (nwg >> 3) + (orig >> 3);
    int m0 = (swz / gridDim.x) * 128, n0 = (swz % gridDim.x) * 128;
    int wave = tid >> 6, lane = tid & 63;
    int wm = (wave >> 1) * 64, wn = (wave & 1) * 64;
    int lr = lane & 15, lg = lane >> 4;
    f32x4 acc[4][4];
    #pragma unroll
    for (int i = 0; i < 4; ++i)
        #pragma unroll
        for (int j = 0; j < 4; ++j) acc[i][j] = (f32x4){0.f, 0.f, 0.f, 0.f};

    int rowS[2], chS[2];
    #pragma unroll
    for (int j = 0; j < 2; ++j) {
        int f = wave * 128 + j * 64 + lane;
        rowS[j] = f >> 2;
        chS[j] = ((f & 3) ^ ((rowS[j] >> 1) & 3)) * 8;
    }
    int rdA[4], rdB[4];
    #pragma unroll
    for (int i = 0; i < 4; ++i) {
        int ra = wm + i * 16 + lr;
        rdA[i] = ra * 32 + (lg ^ ((ra >> 1) & 3)) * 8;
        int rb = wn + i * 16 + lr;
        rdB[i] = rb * 32 + (lg ^ ((rb >> 1) & 3)) * 8;
    }

    const int NT = K >> 5;
    // prologue: stage tiles 0 and 1
    #pragma unroll
    for (int t = 0; t < 2; ++t) {
        #pragma unroll
        for (int j = 0; j < 2; ++j) {
            const unsigned short* srcA = A + (size_t)(m0 + rowS[j]) * K + t * 32 + chS[j];
            __builtin_amdgcn_global_load_lds((gas_cvp)srcA,
                                             (las_vp)(AsP + t * 4096 + wave * 1024 + j * 512), 16, 0, 0);
            const unsigned short* srcB = Wt + (size_t)(n0 + rowS[j]) * K + t * 32 + chS[j];
            __builtin_amdgcn_global_load_lds((gas_cvp)srcB,
                                             (las_vp)(BsP + t * 4096 + wave * 1024 + j * 512), 16, 0, 0);
        }
    }
    int buf = 0;
    for (int kt = 0; kt < NT; ++kt) {
        if (kt + 2 < NT) {
            int nb = (kt + 2) % 3;
            int koff = (kt + 2) * 32;
            #pragma unroll
            for (int j = 0; j < 2; ++j) {
                const unsigned short* srcA = A + (size_t)(m0 + rowS[j]) * K + koff + chS[j];
                __builtin_amdgcn_global_load_lds((gas_cvp)srcA,
                                                 (las_vp)(AsP + nb * 4096 + wave * 1024 + j * 512), 16, 0, 0);
                const unsigned short* srcB = Wt + (size_t)(n0 + rowS[j]) * K + koff + chS[j];
                __builtin_amdgcn_global_load_lds((gas_cvp)srcB,
                                                 (las_vp)(BsP + nb * 4096 + wave * 1024 + j * 512), 16, 0, 0);
            }
        }
        int ahead = NT - 1 - kt;
        if (ahead >= 2)      asm volatile("s_waitcnt vmcnt(8)" ::: "memory");
        else if (ahead == 1) asm volatile("s_waitcnt vmcnt(4)" ::: "memory");
        else                 asm volatile("s_waitcnt vmcnt(0)" ::: "memory");
        __builtin_amdgcn_s_barrier();
        __builtin_amdgcn_sched_barrier(0);
        bf16x8 af[4], bfv[4];
        #pragma unroll
        for (int i = 0; i < 4; ++i) af[i] = *(bf16x8*)&AsP[buf * 4096 + rdA[i]];
        #pragma unroll
        for (int j = 0; j < 4; ++j) bfv[j] = *(bf16x8*)&BsP[buf * 4096 + rdB[j]];
        #pragma unroll
        for (int i = 0; i < 4; ++i)
            #pragma unroll
            for (int j = 0; j < 4; ++j)
                acc[i][j] = __builtin_amdgcn_mfma_f32_16x16x32_bf16(af[i], bfv[j], acc[i][j], 0, 0, 0);
        __builtin_amdgcn_sched_barrier(0);
        __builtin_amdgcn_s_barrier();
        buf = (buf + 1 == 3) ? 0 : buf + 1;
    }

    if (EPI == 1) {
        // scalar f32 epilogue (+bias+res)
        #pragma unroll
        for (int i = 0; i < 4; ++i) {
            #pragma unroll
            for (int j = 0; j < 4; ++j) {
                int col = n0 + wn + j * 16 + lr;
                float bv = bias[col];
                #pragma unroll
                for (int r = 0; r < 4; ++r) {
                    int row = m0 + wm + i * 16 + lg * 4 + r;
                    float c = acc[i][j][r] + bv + res[(size_t)row * Nn + col];
                    ((float*)Cv)[(size_t)row * Nn + col] = c;
                }
            }
        }
    } else {
        // LDS-transposed bf16 epilogue: pool[0,16384) becomes C[128][128] bf16, granule-swizzled.
        #pragma unroll
        for (int i = 0; i < 4; ++i) {
            #pragma unroll
            for (int j = 0; j < 4; ++j) {
                int tcol = wn + j * 16 + lr;
                float bv = bias[n0 + tcol];
                #pragma unroll
                for (int r = 0; r < 4; ++r) {
                    int trow = wm + i * 16 + lg * 4 + r;
                    float c = acc[i][j][r] + bv;
                    if (EPI == 2) {
                        float u = c;
                        float t = 1.5957691216057308f * (u + 0.044715f * u * u * u);
                        c = u / (1.0f + __expf(-t));
                    }
                    pool[trow * 128 + (((tcol >> 3) ^ (trow & 7)) << 3) + (tcol & 7)] = f2b(c);
                }
            }
        }
        __syncthreads();
        #pragma unroll
        for (int cch = 0; cch < 8; ++cch) {
            int g = cch * 256 + tid;          // granule id: 2048 = 128 rows x 16 chunks
            int row = g >> 4, cc = g & 15;
            bf16x8 val = *(bf16x8*)&pool[row * 128 + ((cc ^ (row & 7)) << 3)];
            int grow = m0 + row;
            int gcol = n0 + cc * 8;
            if (EPI == 3) {
                size_t idx = (size_t)(gcol >> 8) * ((size_t)MROWS * DIM) + (size_t)grow * 256 + (gcol & 255);
                *(bf16x8*)((unsigned short*)Cv + idx) = val;
            } else {
                *(bf16x8*)((unsigned short*)Cv + (size_t)grow * Nn + gcol) = val;
            }
        }
    }
}

// ---------------- kmaxg ----------------
__global__ __launch_bounds__(256) void kmaxg_kernel(const unsigned short* __restrict__ k,
                                                    const float* __restrict__ proj,
                                                    float* __restrict__ partial) {
    __shared__ unsigned short As[128][40];
    __shared__ unsigned short Pj[112][40];
    __shared__ float wmax[4][8];
    int tid = threadIdx.x;
    int r0 = blockIdx.x * 128;
    for (int idx = tid; idx < 112 * 8; idx += 256) {
        int m = idx >> 3, f4 = idx & 7;
        if (m < NB) {
            float4 va = *(const float4*)(proj + m * 32 + f4 * 4);
            bf16x4 pk = {(short)f2b(va.x), (short)f2b(va.y), (short)f2b(va.z), (short)f2b(va.w)};
            *(bf16x4*)&Pj[m][f4 * 4] = pk;
        } else {
            *(bf16x4*)&Pj[m][f4 * 4] = (bf16x4){0, 0, 0, 0};
        }
    }
    int arow = tid >> 1, ahalf = tid & 1;
    const unsigned short* ap = k + (size_t)(r0 + arow) * 32 + ahalf * 16;
    *(bf16x8*)&As[arow][ahalf * 16] = *(const bf16x8*)ap;
    *(bf16x8*)&As[arow][ahalf * 16 + 8] = *(const bf16x8*)(ap + 8);
    __syncthreads();
    int wave = tid >> 6, lane = tid & 63, lr = lane & 15, lg = lane >> 4;
    float mymax[4] = {-1e30f, -1e30f, -1e30f, -1e30f};
    #pragma unroll
    for (int mt = 0; mt < 2; ++mt) {
        bf16x8 af = *(bf16x8*)&As[(2 * wave + mt) * 16 + lr][lg * 8];
        #pragma unroll
        for (int nt = 0; nt < 7; ++nt) {
            bf16x8 bfp = *(bf16x8*)&Pj[nt * 16 + lr][lg * 8];
            f32x4 d = (f32x4){0.f, 0.f, 0.f, 0.f};
            d = __builtin_amdgcn_mfma_f32_16x16x32_bf16(af, bfp, d, 0, 0, 0);
            if (!(nt == 6 && lr >= 14)) {
                #pragma unroll
                for (int r = 0; r < 4; ++r) mymax[r] = fmaxf(mymax[r], d[r]);
            }
        }
    }
    #pragma unroll
    for (int r = 0; r < 4; ++r) {
        float v = mymax[r];
        v = fmaxf(v, __shfl_xor(v, 1));
        v = fmaxf(v, __shfl_xor(v, 2));
        v = fmaxf(v, __shfl_xor(v, 4));
        v = fmaxf(v, __shfl_xor(v, 8));
        v = fmaxf(v, __shfl_xor(v, 32));
        mymax[r] = v;
    }
    if (lane == 0 || lane == 16) {
        int hb = (lane >> 4) & 1;
        #pragma unroll
        for (int r = 0; r < 4; ++r) wmax[wave][4 * hb + r] = mymax[r];
    }
    __syncthreads();
    if (tid < 8) {
        float m = fmaxf(fmaxf(wmax[0][tid], wmax[1][tid]), fmaxf(wmax[2][tid], wmax[3][tid]));
        partial[blockIdx.x * 8 + tid] = m * c_dn;
    }
}

// ---------------- kreduce ----------------
__global__ __launch_bounds__(256) void kreduce_kernel(const float* __restrict__ partial,
                                                      float* __restrict__ kmaxf) {
    __shared__ float wred[4];
    int bh = blockIdx.x, b = bh >> 3, h = bh & 7;
    int tid = threadIdx.x;
    float m = fmaxf(partial[(b * 512 + tid) * 8 + h], partial[(b * 512 + 256 + tid) * 8 + h]);
    #pragma unroll
    for (int off = 32; off; off >>= 1) m = fmaxf(m, __shfl_xor(m, off));
    if ((tid & 63) == 0) wred[tid >> 6] = m;
    __syncthreads();
    if (tid == 0)
        kmaxf[bh] = fmaxf(fmaxf(wred[0], wred[1]), fmaxf(wred[2], wred[3]));
}

// ---------------- ctxg ----------------
__global__ __launch_bounds__(256) void ctxg_kernel(const unsigned short* __restrict__ k,
                                                   const unsigned short* __restrict__ v,
                                                   const float* __restrict__ proj,
                                                   const float* __restrict__ kmaxf,
                                                   float* __restrict__ ctx) {
    __shared__ __align__(16) char pool[34816];
    unsigned short (*As)[40] = (unsigned short(*)[40])pool;
    unsigned short (*KpT)[136] = (unsigned short(*)[136])pool;
    __shared__ unsigned short Pj[112][40];
    __shared__ unsigned short VsT[48][136];
    __shared__ float dg[128];
    int tid = threadIdx.x;
    int bh = blockIdx.y, b = bh >> 3, h = bh & 7;
    int n_base = blockIdx.x * 512;
    float mx = kmaxf[bh];
    for (int idx = tid; idx < 112 * 8; idx += 256) {
        int m = idx >> 3, f4 = idx & 7;
        if (m < NB) {
            float4 va = *(const float4*)(proj + m * 32 + f4 * 4);
            bf16x4 pk = {(short)f2b(va.x), (short)f2b(va.y), (short)f2b(va.z), (short)f2b(va.w)};
            *(bf16x4*)&Pj[m][f4 * 4] = pk;
        } else {
            *(bf16x4*)&Pj[m][f4 * 4] = (bf16x4){0, 0, 0, 0};
        }
    }
    for (int idx = tid; idx < 16 * 136; idx += 256) KpT[112 + idx / 136][idx % 136] = 0;
    for (int idx = tid; idx < 16 * 128; idx += 256) {
        int rr = 32 + (idx >> 7), nn = idx & 127;
        VsT[rr][nn] = (rr == 32) ? (unsigned short)0x3F80 : (unsigned short)0;
    }
    int wave = tid >> 6, lane = tid & 63, lr = lane & 15, lg = lane >> 4;
    int arow = tid >> 1, ahalf = tid & 1;
    f32x4 ctxacc[2][3];
    #pragma unroll
    for (int mt = 0; mt < 2; ++mt)
        #pragma unroll
        for (int nt = 0; nt < 3; ++nt) ctxacc[mt][nt] = (f32x4){0.f, 0.f, 0.f, 0.f};

    for (int ni = 0; ni < 4; ++ni) {
        int n0 = n_base + ni * 128;
        {
            const unsigned short* kp_ = k + ((size_t)(b * NSEQ + n0 + arow) * 256 + h * 32 + ahalf * 16);
            bf16x8 k0 = *(const bf16x8*)kp_;
            bf16x8 k1 = *(const bf16x8*)(kp_ + 8);
            *(bf16x8*)&As[arow][ahalf * 16] = k0;
            *(bf16x8*)&As[arow][ahalf * 16 + 8] = k1;
            float ssq = 0.f;
            #pragma unroll
            for (int e = 0; e < 8; ++e) {
                float a = b2f((unsigned short)k0[e]), bb = b2f((unsigned short)k1[e]);
                ssq += a * a + bb * bb;
            }
            ssq += __shfl_xor(ssq, 1);
            if (ahalf == 0) dg[arow] = ssq * c_diagf;
        }
        #pragma unroll
        for (int it = 0; it < 4; ++it) {
            int idx = it * 256 + tid;
            int nn = idx >> 3, f4 = idx & 7;
            bf16x4 vv = *(const bf16x4*)(v + ((size_t)(b * NSEQ + n0 + nn) * 256 + h * 32 + f4 * 4));
            VsT[f4 * 4 + 0][nn] = (unsigned short)vv[0];
            VsT[f4 * 4 + 1][nn] = (unsigned short)vv[1];
            VsT[f4 * 4 + 2][nn] = (unsigned short)vv[2];
            VsT[f4 * 4 + 3][nn] = (unsigned short)vv[3];
        }
        __syncthreads();
        f32x4 xds[2][7];
        #pragma unroll
        for (int mt = 0; mt < 2; ++mt) {
            bf16x8 af = *(bf16x8*)&As[(2 * wave + mt) * 16 + lr][lg * 8];
            #pragma unroll
            for (int nt = 0; nt < 7; ++nt) {
                bf16x8 bfp = *(bf16x8*)&Pj[nt * 16 + lr][lg * 8];
                f32x4 d = (f32x4){0.f, 0.f, 0.f, 0.f};
                xds[mt][nt] = __builtin_amdgcn_mfma_f32_16x16x32_bf16(af, bfp, d, 0, 0, 0);
            }
        }
        __syncthreads();
        #pragma unroll
        for (int mt = 0; mt < 2; ++mt)
            #pragma unroll
            for (int nt = 0; nt < 7; ++nt) {
                int m = nt * 16 + lr;
                #pragma unroll
                for (int r = 0; r < 4; ++r) {
                    int nn = (2 * wave + mt) * 16 + lg * 4 + r;
                    float kpv = (m < NB) ? c_ratio * (__expf(xds[mt][nt][r] * c_dn - dg[nn] - mx) + 1e-4f) : 0.f;
                    KpT[m][nn] = f2b(kpv);
                }
            }
        __syncthreads();
        #pragma unroll
        for (int ks = 0; ks < 4; ++ks)
            #pragma unroll
            for (int mt = 0; mt < 2; ++mt) {
                bf16x8 af2 = *(bf16x8*)&KpT[(2 * wave + mt) * 16 + lr][ks * 32 + lg * 8];
                #pragma unroll
                for (int nt = 0; nt < 3; ++nt) {
                    bf16x8 bf2v = *(bf16x8*)&VsT[nt * 16 + lr][ks * 32 + lg * 8];
                    ctxacc[mt][nt] = __builtin_amdgcn_mfma_f32_16x16x32_bf16(af2, bf2v, ctxacc[mt][nt], 0, 0, 0);
                }
            }
        __syncthreads();
    }
    #pragma unroll
    for (int mt = 0; mt < 2; ++mt)
        #pragma unroll
        for (int nt = 0; nt < 3; ++nt)
            #pragma unroll
            for (int r = 0; r < 4; ++r) {
                int m = (2 * wave + mt) * 16 + lg * 4 + r;
                atomicAdd(&ctx[((size_t)bh * 128 + m) * 48 + nt * 16 + lr], ctxacc[mt][nt][r]);
            }
}

// ---------------- og ----------------
__global__ __launch_bounds__(256) void og_kernel(const unsigned short* __restrict__ q,
                                                 const float* __restrict__ proj,
                                                 const float* __restrict__ ctx,
                                                 unsigned short* __restrict__ o) {
    __shared__ __align__(16) char pool[34816];
    unsigned short (*As)[40] = (unsigned short(*)[40])pool;
    unsigned short (*Qp)[136] = (unsigned short(*)[136])pool;
    __shared__ unsigned short Pj[112][40];
    __shared__ unsigned short CsT[48][136];
    __shared__ float dg[128];
    int tid = threadIdx.x;
    int bh = blockIdx.x >> 6, b = bh >> 3, h = bh & 7;
    int n0 = (blockIdx.x & 63) * 128;
    for (int idx = tid; idx < 112 * 8; idx += 256) {
        int m = idx >> 3, f4 = idx & 7;
        if (m < NB) {
            float4 va = *(const float4*)(proj + m * 32 + f4 * 4);
            bf16x4 pk = {(short)f2b(va.x), (short)f2b(va.y), (short)f2b(va.z), (short)f2b(va.w)};
            *(bf16x4*)&Pj[m][f4 * 4] = pk;
        } else {
            *(bf16x4*)&Pj[m][f4 * 4] = (bf16x4){0, 0, 0, 0};
        }
    }
    for (int idx = tid; idx < 128 * 12; idx += 256) {
        int m = idx / 12, c4 = idx - m * 12;
        float4 cv = *(const float4*)(ctx + ((size_t)bh * 128 + m) * 48 + c4 * 4);
        CsT[c4 * 4 + 0][m] = f2b(cv.x);
        CsT[c4 * 4 + 1][m] = f2b(cv.y);
        CsT[c4 * 4 + 2][m] = f2b(cv.z);
        CsT[c4 * 4 + 3][m] = f2b(cv.w);
    }
    int arow = tid >> 1, ahalf = tid & 1;
    {
        const unsigned short* qp_ = q + ((size_t)(b * NSEQ + n0 + arow) * 256 + h * 32 + ahalf * 16);
        bf16x8 q0 = *(const bf16x8*)qp_;
        bf16x8 q1 = *(const bf16x8*)(qp_ + 8);
        *(bf16x8*)&As[arow][ahalf * 16] = q0;
        *(bf16x8*)&As[arow][ahalf * 16 + 8] = q1;
        float ssq = 0.f;
        #pragma unroll
        for (int e = 0; e < 8; ++e) {
            float a = b2f((unsigned short)q0[e]), bb = b2f((unsigned short)q1[e]);
            ssq += a * a + bb * bb;
        }
        ssq += __shfl_xor(ssq, 1);
        if (ahalf == 0) dg[arow] = ssq * c_diagf;
    }
    __syncthreads();
    int wave = tid >> 6, lane = tid & 63, lr = lane & 15, lg = lane >> 4;
    f32x4 xds[2][7];
    #pragma unroll
    for (int mt = 0; mt < 2; ++mt) {
        bf16x8 af = *(bf16x8*)&As[(2 * wave + mt) * 16 + lr][lg * 8];
        #pragma unroll
        for (int nt = 0; nt < 7; ++nt) {
            bf16x8 bfp = *(bf16x8*)&Pj[nt * 16 + lr][lg * 8];
            f32x4 d = (f32x4){0.f, 0.f, 0.f, 0.f};
            xds[mt][nt] = __builtin_amdgcn_mfma_f32_16x16x32_bf16(af, bfp, d, 0, 0, 0);
        }
    }
    float rmax[2][4];
    #pragma unroll
    for (int mt = 0; mt < 2; ++mt)
        #pragma unroll
        for (int r = 0; r < 4; ++r) {
            float mv = -1e30f;
            #pragma unroll
            for (int nt = 0; nt < 7; ++nt)
                if (!(nt == 6 && lr >= 14)) mv = fmaxf(mv, xds[mt][nt][r]);
            mv = fmaxf(mv, __shfl_xor(mv, 1));
            mv = fmaxf(mv, __shfl_xor(mv, 2));
            mv = fmaxf(mv, __shfl_xor(mv, 4));
            mv = fmaxf(mv, __shfl_xor(mv, 8));
            rmax[mt][r] = mv;
        }
    __syncthreads();
    #pragma unroll
    for (int mt = 0; mt < 2; ++mt)
        #pragma unroll
        for (int r = 0; r < 4; ++r) {
            int row = (2 * wave + mt) * 16 + lg * 4 + r;
            #pragma unroll
            for (int nt = 0; nt < 7; ++nt) {
                int m = nt * 16 + lr;
                float qpv = (m < NB)
                    ? c_ratio * (__expf((xds[mt][nt][r] - rmax[mt][r]) * c_dn - dg[row]) + 1e-4f)
                    : 0.f;
                Qp[row][m] = f2b(qpv);
            }
            Qp[row][112 + lr] = 0;
        }
    __syncthreads();
    f32x4 oacc[2][3];
    #pragma unroll
    for (int mt = 0; mt < 2; ++mt)
        #pragma unroll
        for (int nt = 0; nt < 3; ++nt) oacc[mt][nt] = (f32x4){0.f, 0.f, 0.f, 0.f};
    #pragma unroll
    for (int ks = 0; ks < 4; ++ks)
        #pragma unroll
        for (int mt = 0; mt < 2; ++mt) {
            bf16x8 af2 = *(bf16x8*)&Qp[(2 * wave + mt) * 16 + lr][ks * 32 + lg * 8];
            #pragma unroll
            for (int nt = 0; nt < 3; ++nt) {
                bf16x8 bf2v = *(bf16x8*)&CsT[nt * 16 + lr][ks * 32 + lg * 8];
                oacc[mt][nt] = __builtin_amdgcn_mfma_f32_16x16x32_bf16(af2, bf2v, oacc[mt][nt], 0, 0, 0);
            }
        }
    #pragma unroll
    for (int mt = 0; mt < 2; ++mt)
        #pragma unroll
        for (int r = 0; r < 4; ++r) {
            int row = (2 * wave + mt) * 16 + lg * 4 + r;
            int n = n0 + row;
            float den = __shfl(oacc[mt][2][r], lane & 48);
            float inv = 1.0f / den;
            size_t base = (size_t)(b * NSEQ + n) * 256 + h * 32;
            o[base + lr] = f2b(oacc[mt][0][r] * inv);
            o[base + 16 + lr] = f2b(oacc[mt][1][r] * inv);
        }
}

extern "C" void kernel_launch(void* const* d_in, const int* in_sizes, int n_in,
                              void* d_out, int out_size, void* d_ws, size_t ws_size,
                              hipStream_t stream) {
    const float* x = (const float*)d_in[0];
    const float* proj = (const float*)d_in[1];
    const float* ln1_g = (const float*)d_in[2];
    const float* ln1_b = (const float*)d_in[3];
    const float* Wq = (const float*)d_in[4];
    const float* bq = (const float*)d_in[5];
    const float* Wk = (const float*)d_in[6];
    const float* bk = (const float*)d_in[7];
    const float* Wv = (const float*)d_in[8];
    const float* bv = (const float*)d_in[9];
    const float* Wo = (const float*)d_in[10];
    const float* bo = (const float*)d_in[11];
    const float* ln2_g = (const float*)d_in[12];
    const float* ln2_b = (const float*)d_in[13];
    const float* Wf1 = (const float*)d_in[14];
    const float* bf1 = (const float*)d_in[15];
    const float* Wf2 = (const float*)d_in[16];
    const float* bf2 = (const float*)d_in[17];

    float* h = (float*)d_out;
    const size_t ACT = (size_t)MROWS * DIM;
    unsigned short* y = (unsigned short*)d_ws;
    unsigned short* q = y + ACT;
    unsigned short* k = q + ACT;
    unsigned short* v = k + ACT;
    unsigned short* mid = v + ACT;                   // [32768][1024] bf16
    float* ctx = (float*)(mid + 4 * ACT);
    float* kmaxf = ctx + (size_t)BH * 128 * 48;
    float* partial = kmaxf + 32;                     // 2048*8 floats
    float* bqkv = partial + 2048 * 8;                // 4*768 floats
    unsigned short* wt = (unsigned short*)(bqkv + 4 * 768);
    unsigned short* o = y;

    const int WT_L = 786432;
    const int CTXN = BH * 128 * 48;

    copy4_kernel<<<(int)(ACT / 4) / 256, 256, 0, stream>>>((const float4*)x, (float4*)h, (int)(ACT / 4));

    wt_kernel<<<dim3(8, 8, 4), 256, 0, stream>>>(Wq, wt + 0, 256, 256, WT_L);
    wt_kernel<<<dim3(8, 8, 4), 256, 0, stream>>>(Wk, wt + 65536, 256, 256, WT_L);
    wt_kernel<<<dim3(8, 8, 4), 256, 0, stream>>>(Wv, wt + 131072, 256, 256, WT_L);
    wt_kernel<<<dim3(8, 8, 4), 256, 0, stream>>>(Wo, wt + 196608, 256, 256, WT_L);
    wt_kernel<<<dim3(8, 32, 4), 256, 0, stream>>>(Wf1, wt + 262144, 256, 1024, WT_L);
    wt_kernel<<<dim3(32, 8, 4), 256, 0, stream>>>(Wf2, wt + 524288, 1024, 256, WT_L);
    bcat_kernel<<<4, 256, 0, stream>>>(bq, bk, bv, bqkv);

    for (int i = 0; i < 4; ++i) {
        const float* proj_i = proj + (size_t)i * NB * DHEAD;
        const unsigned short* wl = wt + (size_t)i * WT_L;
        // --- attention ---
        ln_kernel<<<MROWS / 4, 256, 0, stream>>>(h, ln1_g + i * DIM, ln1_b + i * DIM, y);
        gemm_mfma<3><<<dim3(6, 256), 256, 0, stream>>>(y, wl + 0, bqkv + i * 768, nullptr, q, 768, DIM);

        zero_kernel<<<(CTXN + 255) / 256, 256, 0, stream>>>(ctx, CTXN);
        kmaxg_kernel<<<2048, 256, 0, stream>>>(k, proj_i, partial);
        kreduce_kernel<<<BH, 256, 0, stream>>>(partial, kmaxf);
        ctxg_kernel<<<dim3(16, BH), 256, 0, stream>>>(k, v, proj_i, kmaxf, ctx);
        og_kernel<<<BH * 64, 256, 0, stream>>>(q, proj_i, ctx, o);

        gemm_mfma<1><<<dim3(2, 256), 256, 0, stream>>>(o, wl + 196608, bo + i * DIM, h, h, DIM, INNER);

        // --- FFN ---
        ln_kernel<<<MROWS / 4, 256, 0, stream>>>(h, ln2_g + i * DIM, ln2_b + i * DIM, y);
        gemm_mfma<2><<<dim3(8, 256), 256, 0, stream>>>(y, wl + 262144, bf1 + i * FFDIM, nullptr, mid, FFDIM, DIM);
        gemm_mfma<1><<<dim3(2, 256), 256, 0, stream>>>(mid, wl + 524288, bf2 + i * DIM, h, h, DIM, FFDIM);
    }
}